// Round 2
// baseline (744.296 us; speedup 1.0000x reference)
//
#include <hip/hip_runtime.h>
#include <hip/hip_bf16.h>

// B=16, N=512, D=512, H=8, HD=64, K(topk)=16, MSL=512
#define BB 16
#define NN 512
#define DD 512
#define HH 8
#define HD 64
#define MM (BB*NN)      // 8192 rows
#define DFF 2048

typedef __attribute__((ext_vector_type(8))) short bf16x8;
typedef __attribute__((ext_vector_type(4))) float fx4;

static __device__ __forceinline__ unsigned short f2bf(float f) {
  unsigned u = __float_as_uint(f);
  u += 0x7FFFu + ((u >> 16) & 1u);   // RNE
  return (unsigned short)(u >> 16);
}
static __device__ __forceinline__ float bf2f(unsigned short s) {
  return __uint_as_float(((unsigned)s) << 16);
}

// ---------------- weight transpose: in[K][N] fp32 -> out[N][K] bf16 ----------------
__global__ void transpose_bf16(const float* __restrict__ in, unsigned short* __restrict__ out,
                               int K, int N) {
  __shared__ float tl[32][33];
  int tx = threadIdx.x, ty = threadIdx.y;        // (32,8)
  int x0 = blockIdx.x * 32, y0 = blockIdx.y * 32;
  #pragma unroll
  for (int i = 0; i < 4; i++)
    tl[ty + i*8][tx] = in[(size_t)(y0 + ty + i*8) * N + x0 + tx];
  __syncthreads();
  #pragma unroll
  for (int i = 0; i < 4; i++)
    out[(size_t)(x0 + ty + i*8) * K + y0 + tx] = f2bf(tl[tx][ty + i*8]);
}

__global__ void concat_bias(const float* __restrict__ bq, const float* __restrict__ bk,
                            const float* __restrict__ bv, float* __restrict__ o) {
  int t = blockIdx.x * 256 + threadIdx.x;
  if (t < 512) o[t] = bq[t];
  else if (t < 1024) o[t] = bk[t - 512];
  else if (t < 1536) o[t] = bv[t - 1024];
}

// ---------------- LayerNorm: fp32 [rows][512] -> bf16 ----------------
__global__ __launch_bounds__(256) void ln_kernel(const float* __restrict__ X,
                                                 const float* __restrict__ g,
                                                 const float* __restrict__ be,
                                                 unsigned short* __restrict__ O) {
  int w = threadIdx.x >> 6, l = threadIdx.x & 63;
  size_t row = (size_t)blockIdx.x * 4 + w;
  const float* xr = X + row * 512;
  fx4 a = *(const fx4*)(xr + l*4);
  fx4 c = *(const fx4*)(xr + 256 + l*4);
  float s = a[0]+a[1]+a[2]+a[3] + c[0]+c[1]+c[2]+c[3];
  float q = a[0]*a[0]+a[1]*a[1]+a[2]*a[2]+a[3]*a[3]
          + c[0]*c[0]+c[1]*c[1]+c[2]*c[2]+c[3]*c[3];
  #pragma unroll
  for (int s2 = 1; s2 < 64; s2 <<= 1) { s += __shfl_xor(s, s2); q += __shfl_xor(q, s2); }
  float mean = s * (1.0f/512.0f);
  float var  = q * (1.0f/512.0f) - mean*mean;
  float rs = rsqrtf(var + 1e-5f);
  fx4 ga = *(const fx4*)(g + l*4);
  fx4 gc = *(const fx4*)(g + 256 + l*4);
  fx4 ba = *(const fx4*)(be + l*4);
  fx4 bc = *(const fx4*)(be + 256 + l*4);
  ushort4 o1, o2;
  o1.x = f2bf((a[0]-mean)*rs*ga[0] + ba[0]);
  o1.y = f2bf((a[1]-mean)*rs*ga[1] + ba[1]);
  o1.z = f2bf((a[2]-mean)*rs*ga[2] + ba[2]);
  o1.w = f2bf((a[3]-mean)*rs*ga[3] + ba[3]);
  o2.x = f2bf((c[0]-mean)*rs*gc[0] + bc[0]);
  o2.y = f2bf((c[1]-mean)*rs*gc[1] + bc[1]);
  o2.z = f2bf((c[2]-mean)*rs*gc[2] + bc[2]);
  o2.w = f2bf((c[3]-mean)*rs*gc[3] + bc[3]);
  *(ushort4*)(O + row*512 + l*4) = o1;
  *(ushort4*)(O + row*512 + 256 + l*4) = o2;
}

// ---------------- GEMM: C = A[M][K](bf16) x B^T rows [N][K](bf16) + epilogue ----------------
// MODE 0: +bqkv, cols<512 scaled by 0.125, out bf16   (QKV)
// MODE 1: +bias +resid -> fp32                        (out-proj + residual)
// MODE 2: +bias, exact GELU -> bf16                   (FFN1)
// MODE 3: +bias +resid -> fp32                        (FFN2 -> d_out; resid MAY ALIAS C)
template<int MODE>
__global__ __launch_bounds__(256) void gemm_kernel(
    const unsigned short* __restrict__ A,
    const unsigned short* __restrict__ Bm,
    const float* __restrict__ bias,
    const float* resid,           // no __restrict__: MODE 3 aliases resid == C
    void* C,
    int M, int N, int K) {
  __shared__ unsigned short As[128*40];   // stride 40 bf16 (80B, 16B aligned, ~2-way banks)
  __shared__ unsigned short Bs[128*40];
  int m0 = blockIdx.y * 128, n0 = blockIdx.x * 128;
  int t = threadIdx.x;
  int w = t >> 6, l = t & 63;
  int wm = w >> 1, wn = w & 1;
  int lid = l & 15, quad = l >> 4;

  fx4 acc[4][4];
  #pragma unroll
  for (int i = 0; i < 4; i++)
    #pragma unroll
    for (int j = 0; j < 4; j++) acc[i][j] = (fx4){0.f,0.f,0.f,0.f};

  for (int k0 = 0; k0 < K; k0 += 32) {
    #pragma unroll
    for (int i = 0; i < 2; i++) {
      int c = t + i*256;
      int row = c >> 2, ch = c & 3;
      uint4 da = *(const uint4*)(A  + (size_t)(m0+row)*K + k0 + ch*8);
      uint4 db = *(const uint4*)(Bm + (size_t)(n0+row)*K + k0 + ch*8);
      *(uint4*)(As + row*40 + ch*8) = da;
      *(uint4*)(Bs + row*40 + ch*8) = db;
    }
    __syncthreads();
    bf16x8 af[4], bf[4];
    #pragma unroll
    for (int i = 0; i < 4; i++) {
      af[i] = *(const bf16x8*)(As + (wm*64 + i*16 + lid)*40 + quad*8);
      bf[i] = *(const bf16x8*)(Bs + (wn*64 + i*16 + lid)*40 + quad*8);
    }
    #pragma unroll
    for (int i = 0; i < 4; i++)
      #pragma unroll
      for (int j = 0; j < 4; j++)
        acc[i][j] = __builtin_amdgcn_mfma_f32_16x16x32_bf16(af[i], bf[j], acc[i][j], 0, 0, 0);
    __syncthreads();
  }

  #pragma unroll
  for (int i = 0; i < 4; i++) {
    #pragma unroll
    for (int j = 0; j < 4; j++) {
      int col = n0 + wn*64 + j*16 + lid;
      float bv = bias[col];
      #pragma unroll
      for (int r = 0; r < 4; r++) {
        int row = m0 + wm*64 + i*16 + quad*4 + r;
        float v = acc[i][j][r] + bv;
        if (MODE == 0) {
          if (col < 512) v *= 0.125f;   // fold HD^-0.5 into Q
          ((unsigned short*)C)[(size_t)row*N + col] = f2bf(v);
        } else if (MODE == 1 || MODE == 3) {
          v += resid[(size_t)row*N + col];
          ((float*)C)[(size_t)row*N + col] = v;
        } else {  // MODE 2: exact GELU
          float gl = 0.5f * v * (1.0f + erff(v * 0.70710678118654752f));
          ((unsigned short*)C)[(size_t)row*N + col] = f2bf(gl);
        }
      }
    }
  }
}

// ---------------- fused attention: QK^T (MFMA) + rel bias + exact top-16 softmax + sparse PV ----------
// grid: 1024 blocks = (b,h) x 8 query-chunks of 64; block 256 thr = 4 waves x 16 queries
__global__ __launch_bounds__(256) void attn_kernel(
    const unsigned short* __restrict__ QKV,   // [8192][1536] bf16, Q pre-scaled
    const float* __restrict__ rel_emb,        // [1023][8]
    unsigned short* __restrict__ Aout) {      // [8192][512] bf16
  __shared__ float smem[10240];               // 40KB
  unsigned short* Ks = (unsigned short*)smem; // [256][72] bf16 (floats 0..9215)
  float* bias_s = smem + 9216;                // [1023]
  int blk = blockIdx.x;
  int q0 = (blk & 7) << 6;
  int bh = blk >> 3;
  int b = bh >> 3, h = bh & 7;
  int t = threadIdx.x;
  int w = t >> 6, l = t & 63;
  int lid = l & 15, quad = l >> 4;

  for (int i = t; i < 1023; i += 256) bias_s[i] = rel_emb[i*8 + h];

  // Q fragments (A operand: m=lane&15, k=quad*8+j), two 32-wide k halves
  int qn = q0 + w*16 + lid;
  const unsigned short* qp = QKV + ((size_t)(b*512 + qn))*1536 + h*64 + quad*8;
  bf16x8 qf0 = *(const bf16x8*)qp;
  bf16x8 qf1 = *(const bf16x8*)(qp + 32);

  fx4 acc[32];
  #pragma unroll
  for (int i = 0; i < 32; i++) acc[i] = (fx4){0.f,0.f,0.f,0.f};

  #pragma unroll
  for (int half = 0; half < 2; half++) {
    __syncthreads();
    #pragma unroll
    for (int i = 0; i < 8; i++) {        // stage 256 keys x 64 dims bf16
      int c = t + i*256;
      int row = c >> 3, ch = c & 7;
      uint4 d = *(const uint4*)(QKV + ((size_t)(b*512 + half*256 + row))*1536 + 512 + h*64 + ch*8);
      *(uint4*)(Ks + row*72 + ch*8) = d;
    }
    __syncthreads();
    #pragma unroll
    for (int kt = 0; kt < 16; kt++) {
      const unsigned short* kp = Ks + (kt*16 + lid)*72 + quad*8;
      bf16x8 kb0 = *(const bf16x8*)kp;
      bf16x8 kb1 = *(const bf16x8*)(kp + 32);
      int ai = half*16 + kt;
      acc[ai] = __builtin_amdgcn_mfma_f32_16x16x32_bf16(qf0, kb0, acc[ai], 0, 0, 0);
      acc[ai] = __builtin_amdgcn_mfma_f32_16x16x32_bf16(qf1, kb1, acc[ai], 0, 0, 0);
    }
  }
  __syncthreads();   // K buffer dead; alias as row buffer

  float* Lw = smem + w*2080;           // per-wave [4 rows][520]
  float* pr = smem + 8320 + w*32;      // per-wave 16 e + 16 m

  #pragma unroll
  for (int r = 0; r < 4; r++) {
    // spill 4 rows (quad-indexed) of logits + bias to LDS
    int nq = q0 + w*16 + quad*4 + r;
    #pragma unroll
    for (int kt = 0; kt < 32; kt++) {
      int m = kt*16 + lid;
      Lw[quad*520 + m] = acc[kt][r] + bias_s[m - nq + 511];
    }
    __threadfence_block();
    #pragma unroll 1
    for (int g = 0; g < 4; g++) {
      int n = q0 + w*16 + g*4 + r;
      // pack: 23-bit monotonic value | 9-bit complemented index (unique, exact tie-break)
      unsigned pk[8], pks[8];
      #pragma unroll
      for (int j = 0; j < 8; j++) {
        int m = l + j*64;
        unsigned mu = __float_as_uint(Lw[g*520 + m]);
        mu = (mu & 0x80000000u) ? ~mu : (mu | 0x80000000u);
        unsigned v2 = (mu & 0xFFFFFE00u) | (unsigned)(511 - m);
        pk[j] = v2; pks[j] = v2;
      }
      float vmax = 0.f, esum = 0.f;
      unsigned thr = 0;
      #pragma unroll 1
      for (int k = 0; k < 16; k++) {   // exact top-16 extraction
        unsigned best = pk[0];
        #pragma unroll
        for (int j = 1; j < 8; j++) best = pk[j] > best ? pk[j] : best;
        #pragma unroll
        for (int s2 = 1; s2 < 64; s2 <<= 1) {
          unsigned o2 = __shfl_xor(best, s2);
          best = o2 > best ? o2 : best;
        }
        unsigned vu = best & 0xFFFFFE00u;
        vu = (vu & 0x80000000u) ? (vu & 0x7FFFFFFFu) : ~vu;
        float v = __uint_as_float(vu);
        if (k == 0) vmax = v;
        esum += exp2f((v - vmax) * 1.44269504f);
        thr = best;
        #pragma unroll
        for (int j = 0; j < 8; j++) pk[j] = (pk[j] == best) ? 0u : pk[j];
      }
      // compact the exactly-16 survivors (packed keys unique => count(>=thr)==16)
      unsigned long long below = (1ull << l) - 1ull;
      int base = 0;
      #pragma unroll
      for (int j = 0; j < 8; j++) {
        bool sel = pks[j] >= thr;
        unsigned long long mask = __ballot(sel);
        if (sel) {
          int slot = base + (int)__popcll(mask & below);
          unsigned vu2 = pks[j] & 0xFFFFFE00u;
          vu2 = (vu2 & 0x80000000u) ? (vu2 & 0x7FFFFFFFu) : ~vu2;
          float vv = __uint_as_float(vu2);
          pr[slot] = exp2f((vv - vmax) * 1.44269504f);
          ((int*)pr)[16 + slot] = 511 - (int)(pks[j] & 0x1FFu);
        }
        base += (int)__popcll(mask);
      }
      __threadfence_block();
      // sparse PV: lane = head dim
      float o = 0.f;
      float inv = 1.0f / esum;
      #pragma unroll
      for (int k2 = 0; k2 < 16; k2++) {
        float e = pr[k2];
        int m = ((const int*)pr)[16 + k2];
        o += e * bf2f(QKV[((size_t)(b*512 + m))*1536 + 1024 + h*64 + l]);
      }
      Aout[((size_t)(b*512 + n))*512 + h*64 + l] = f2bf(o * inv);
      __threadfence_block();   // pr reused next g
    }
  }
}

// ---------------- host ----------------
// ws budget (lifetime-aliased, ~46 MB total — R1 overflow corrupted pristine
// inputs when layout used ~102 MB):
//   W: weights bf16 (wqkvT 1.5M, woT 0.5M, w1T 2M, w2T 2M, bqkv 6K)
//   R1 (8 MB):  xn1 (ln1->gemm0) -> aout (attn->gemm1) -> xn2 (ln2->gemm2)
//   R2 (32 MB): qkvb in first 24 MB (gemm0->attn) -> hbuf full 32 MB (gemm2->gemm3)
//   x2 lives in d_out (gemm1 writes, ln2 reads, gemm3 same-addr RMW per element)
extern "C" void kernel_launch(void* const* d_in, const int* in_sizes, int n_in,
                              void* d_out, int out_size, void* d_ws, size_t ws_size,
                              hipStream_t stream) {
  const float* x   = (const float*)d_in[0];
  const float* wq  = (const float*)d_in[1];
  const float* bq  = (const float*)d_in[2];
  const float* wk  = (const float*)d_in[3];
  const float* bk  = (const float*)d_in[4];
  const float* wv  = (const float*)d_in[5];
  const float* bv  = (const float*)d_in[6];
  const float* wo  = (const float*)d_in[7];
  const float* bo  = (const float*)d_in[8];
  const float* g1  = (const float*)d_in[9];
  const float* be1 = (const float*)d_in[10];
  const float* g2  = (const float*)d_in[11];
  const float* be2 = (const float*)d_in[12];
  const float* w1  = (const float*)d_in[13];
  const float* bf1 = (const float*)d_in[14];
  const float* w2  = (const float*)d_in[15];
  const float* bf2 = (const float*)d_in[16];
  const float* rel = (const float*)d_in[17];

  char* p = (char*)d_ws;
  size_t off = 0;
  auto alloc = [&](size_t bytes) {
    size_t cur = off;
    off += (bytes + 255) & ~(size_t)255;
    return (void*)(p + cur);
  };
  unsigned short* wqkvT = (unsigned short*)alloc((size_t)1536*512*2);
  unsigned short* woT   = (unsigned short*)alloc((size_t)512*512*2);
  unsigned short* w1T   = (unsigned short*)alloc((size_t)2048*512*2);
  unsigned short* w2T   = (unsigned short*)alloc((size_t)512*2048*2);
  float*          bqkv  = (float*)alloc(1536*4);
  unsigned short* R1    = (unsigned short*)alloc((size_t)MM*512*2);   // 8MB
  unsigned short* R2    = (unsigned short*)alloc((size_t)MM*2048*2);  // 32MB

  unsigned short* xn1  = R1;                    // ln1 -> gemm0
  unsigned short* aout = R1;                    // attn -> gemm1 (xn1 dead)
  unsigned short* xn2  = R1;                    // ln2 -> gemm2 (aout dead)
  unsigned short* qkvb = R2;                    // gemm0 -> attn (24MB of 32)
  unsigned short* hbuf = R2;                    // gemm2 -> gemm3 (qkvb dead)
  float*          x2   = (float*)d_out;         // gemm1 -> ln2/gemm3
  (void)ws_size; (void)in_sizes; (void)n_in; (void)out_size;

  dim3 tb(32, 8);
  transpose_bf16<<<dim3(16, 16), tb, 0, stream>>>(wq, wqkvT,             512, 512);
  transpose_bf16<<<dim3(16, 16), tb, 0, stream>>>(wk, wqkvT + 512*512,   512, 512);
  transpose_bf16<<<dim3(16, 16), tb, 0, stream>>>(wv, wqkvT + 2*512*512, 512, 512);
  transpose_bf16<<<dim3(16, 16), tb, 0, stream>>>(wo, woT,               512, 512);
  transpose_bf16<<<dim3(64, 16), tb, 0, stream>>>(w1, w1T,  512, 2048);
  transpose_bf16<<<dim3(16, 64), tb, 0, stream>>>(w2, w2T, 2048,  512);
  concat_bias<<<6, 256, 0, stream>>>(bq, bk, bv, bqkv);

  ln_kernel<<<2048, 256, 0, stream>>>(x, g1, be1, xn1);
  gemm_kernel<0><<<dim3(12, 64), 256, 0, stream>>>(xn1, wqkvT, bqkv, nullptr, qkvb, MM, 1536, 512);
  attn_kernel<<<1024, 256, 0, stream>>>(qkvb, rel, aout);
  gemm_kernel<1><<<dim3(4, 64), 256, 0, stream>>>(aout, woT, bo, x, x2, MM, 512, 512);
  ln_kernel<<<2048, 256, 0, stream>>>(x2, g2, be2, xn2);
  gemm_kernel<2><<<dim3(16, 64), 256, 0, stream>>>(xn2, w1T, bf1, nullptr, hbuf, MM, 2048, 512);
  gemm_kernel<3><<<dim3(4, 64), 256, 0, stream>>>(hbuf, w2T, bf2, x2, (float*)d_out, MM, 512, 2048);
}

// Round 3
// 566.304 us; speedup vs baseline: 1.3143x; 1.3143x over previous
//
#include <hip/hip_runtime.h>
#include <hip/hip_bf16.h>

// B=16, N=512, D=512, H=8, HD=64, K(topk)=16, MSL=512
#define BB 16
#define NN 512
#define DD 512
#define HH 8
#define HD 64
#define MM (BB*NN)      // 8192 rows
#define DFF 2048

typedef __attribute__((ext_vector_type(8))) short bf16x8;
typedef __attribute__((ext_vector_type(4))) float fx4;

static __device__ __forceinline__ unsigned short f2bf(float f) {
  unsigned u = __float_as_uint(f);
  u += 0x7FFFu + ((u >> 16) & 1u);   // RNE
  return (unsigned short)(u >> 16);
}
static __device__ __forceinline__ float bf2f(unsigned short s) {
  return __uint_as_float(((unsigned)s) << 16);
}

// ---------------- weight transpose: in[K][N] fp32 -> out[N][K] bf16 ----------------
__global__ void transpose_bf16(const float* __restrict__ in, unsigned short* __restrict__ out,
                               int K, int N) {
  __shared__ float tl[32][33];
  int tx = threadIdx.x, ty = threadIdx.y;        // (32,8)
  int x0 = blockIdx.x * 32, y0 = blockIdx.y * 32;
  #pragma unroll
  for (int i = 0; i < 4; i++)
    tl[ty + i*8][tx] = in[(size_t)(y0 + ty + i*8) * N + x0 + tx];
  __syncthreads();
  #pragma unroll
  for (int i = 0; i < 4; i++)
    out[(size_t)(x0 + ty + i*8) * K + y0 + tx] = f2bf(tl[tx][ty + i*8]);
}

__global__ void concat_bias(const float* __restrict__ bq, const float* __restrict__ bk,
                            const float* __restrict__ bv, float* __restrict__ o) {
  int t = blockIdx.x * 256 + threadIdx.x;
  if (t < 512) o[t] = bq[t];
  else if (t < 1024) o[t] = bk[t - 512];
  else if (t < 1536) o[t] = bv[t - 1024];
}

// ---------------- LayerNorm: fp32 [rows][512] -> bf16 ----------------
__global__ __launch_bounds__(256) void ln_kernel(const float* __restrict__ X,
                                                 const float* __restrict__ g,
                                                 const float* __restrict__ be,
                                                 unsigned short* __restrict__ O) {
  int w = threadIdx.x >> 6, l = threadIdx.x & 63;
  size_t row = (size_t)blockIdx.x * 4 + w;
  const float* xr = X + row * 512;
  fx4 a = *(const fx4*)(xr + l*4);
  fx4 c = *(const fx4*)(xr + 256 + l*4);
  float s = a[0]+a[1]+a[2]+a[3] + c[0]+c[1]+c[2]+c[3];
  float q = a[0]*a[0]+a[1]*a[1]+a[2]*a[2]+a[3]*a[3]
          + c[0]*c[0]+c[1]*c[1]+c[2]*c[2]+c[3]*c[3];
  #pragma unroll
  for (int s2 = 1; s2 < 64; s2 <<= 1) { s += __shfl_xor(s, s2); q += __shfl_xor(q, s2); }
  float mean = s * (1.0f/512.0f);
  float var  = q * (1.0f/512.0f) - mean*mean;
  float rs = rsqrtf(var + 1e-5f);
  fx4 ga = *(const fx4*)(g + l*4);
  fx4 gc = *(const fx4*)(g + 256 + l*4);
  fx4 ba = *(const fx4*)(be + l*4);
  fx4 bc = *(const fx4*)(be + 256 + l*4);
  ushort4 o1, o2;
  o1.x = f2bf((a[0]-mean)*rs*ga[0] + ba[0]);
  o1.y = f2bf((a[1]-mean)*rs*ga[1] + ba[1]);
  o1.z = f2bf((a[2]-mean)*rs*ga[2] + ba[2]);
  o1.w = f2bf((a[3]-mean)*rs*ga[3] + ba[3]);
  o2.x = f2bf((c[0]-mean)*rs*gc[0] + bc[0]);
  o2.y = f2bf((c[1]-mean)*rs*gc[1] + bc[1]);
  o2.z = f2bf((c[2]-mean)*rs*gc[2] + bc[2]);
  o2.w = f2bf((c[3]-mean)*rs*gc[3] + bc[3]);
  *(ushort4*)(O + row*512 + l*4) = o1;
  *(ushort4*)(O + row*512 + 256 + l*4) = o2;
}

// ---------------- GEMM: C = A[M][K](bf16) x B^T rows [N][K](bf16) + epilogue ----------------
// MODE 0: +bqkv, cols<512 scaled by 0.125, out bf16   (QKV)
// MODE 1: +bias +resid -> fp32                        (out-proj + residual)
// MODE 2: +bias, exact GELU -> bf16                   (FFN1)
// MODE 3: +bias +resid -> fp32                        (FFN2 -> d_out; resid MAY ALIAS C)
template<int MODE>
__global__ __launch_bounds__(256) void gemm_kernel(
    const unsigned short* __restrict__ A,
    const unsigned short* __restrict__ Bm,
    const float* __restrict__ bias,
    const float* resid,           // no __restrict__: MODE 3 aliases resid == C
    void* C,
    int M, int N, int K) {
  __shared__ unsigned short As[128*40];   // stride 40 bf16 (80B, 16B aligned, ~2-way banks)
  __shared__ unsigned short Bs[128*40];
  int m0 = blockIdx.y * 128, n0 = blockIdx.x * 128;
  int t = threadIdx.x;
  int w = t >> 6, l = t & 63;
  int wm = w >> 1, wn = w & 1;
  int lid = l & 15, quad = l >> 4;

  fx4 acc[4][4];
  #pragma unroll
  for (int i = 0; i < 4; i++)
    #pragma unroll
    for (int j = 0; j < 4; j++) acc[i][j] = (fx4){0.f,0.f,0.f,0.f};

  for (int k0 = 0; k0 < K; k0 += 32) {
    #pragma unroll
    for (int i = 0; i < 2; i++) {
      int c = t + i*256;
      int row = c >> 2, ch = c & 3;
      uint4 da = *(const uint4*)(A  + (size_t)(m0+row)*K + k0 + ch*8);
      uint4 db = *(const uint4*)(Bm + (size_t)(n0+row)*K + k0 + ch*8);
      *(uint4*)(As + row*40 + ch*8) = da;
      *(uint4*)(Bs + row*40 + ch*8) = db;
    }
    __syncthreads();
    bf16x8 af[4], bf[4];
    #pragma unroll
    for (int i = 0; i < 4; i++) {
      af[i] = *(const bf16x8*)(As + (wm*64 + i*16 + lid)*40 + quad*8);
      bf[i] = *(const bf16x8*)(Bs + (wn*64 + i*16 + lid)*40 + quad*8);
    }
    #pragma unroll
    for (int i = 0; i < 4; i++)
      #pragma unroll
      for (int j = 0; j < 4; j++)
        acc[i][j] = __builtin_amdgcn_mfma_f32_16x16x32_bf16(af[i], bf[j], acc[i][j], 0, 0, 0);
    __syncthreads();
  }

  #pragma unroll
  for (int i = 0; i < 4; i++) {
    #pragma unroll
    for (int j = 0; j < 4; j++) {
      int col = n0 + wn*64 + j*16 + lid;
      float bv = bias[col];
      #pragma unroll
      for (int r = 0; r < 4; r++) {
        int row = m0 + wm*64 + i*16 + quad*4 + r;
        float v = acc[i][j][r] + bv;
        if (MODE == 0) {
          if (col < 512) v *= 0.125f;   // fold HD^-0.5 into Q
          ((unsigned short*)C)[(size_t)row*N + col] = f2bf(v);
        } else if (MODE == 1 || MODE == 3) {
          v += resid[(size_t)row*N + col];
          ((float*)C)[(size_t)row*N + col] = v;
        } else {  // MODE 2: exact GELU
          float gl = 0.5f * v * (1.0f + erff(v * 0.70710678118654752f));
          ((unsigned short*)C)[(size_t)row*N + col] = f2bf(gl);
        }
      }
    }
  }
}

// ---------------- fused attention: QK^T (MFMA) + rel bias + exact top-16 softmax + sparse PV ----------
// grid: 1024 blocks = (b,h) x 8 query-chunks of 64; block 256 thr = 4 waves x 16 queries
// R3: top-16 via scalar binary-search threshold (count>=T by ballot+popc), replacing
//     16 sequential 6-deep shuffle-reduce extractions (latency-bound, VALUBusy was 23%).
//     Exact: packed keys (23b value | 9b ~index) are unique, so any T with count==16
//     selects precisely the top-16 set (ties broken by lower index, matching lax.top_k).
__global__ __launch_bounds__(256) void attn_kernel(
    const unsigned short* __restrict__ QKV,   // [8192][1536] bf16, Q pre-scaled
    const float* __restrict__ rel_emb,        // [1023][8]
    unsigned short* __restrict__ Aout) {      // [8192][512] bf16
  __shared__ float smem[10240];               // 40KB
  unsigned short* Ks = (unsigned short*)smem; // [256][72] bf16 (floats 0..9215)
  float* bias_s = smem + 9216;                // [1023]
  int blk = blockIdx.x;
  int q0 = (blk & 7) << 6;
  int bh = blk >> 3;
  int b = bh >> 3, h = bh & 7;
  int t = threadIdx.x;
  int w = t >> 6, l = t & 63;
  int lid = l & 15, quad = l >> 4;

  for (int i = t; i < 1023; i += 256) bias_s[i] = rel_emb[i*8 + h];

  // Q fragments (A operand: m=lane&15, k=quad*8+j), two 32-wide k halves
  int qn = q0 + w*16 + lid;
  const unsigned short* qp = QKV + ((size_t)(b*512 + qn))*1536 + h*64 + quad*8;
  bf16x8 qf0 = *(const bf16x8*)qp;
  bf16x8 qf1 = *(const bf16x8*)(qp + 32);

  fx4 acc[32];
  #pragma unroll
  for (int i = 0; i < 32; i++) acc[i] = (fx4){0.f,0.f,0.f,0.f};

  #pragma unroll
  for (int half = 0; half < 2; half++) {
    __syncthreads();
    #pragma unroll
    for (int i = 0; i < 8; i++) {        // stage 256 keys x 64 dims bf16
      int c = t + i*256;
      int row = c >> 3, ch = c & 7;
      uint4 d = *(const uint4*)(QKV + ((size_t)(b*512 + half*256 + row))*1536 + 512 + h*64 + ch*8);
      *(uint4*)(Ks + row*72 + ch*8) = d;
    }
    __syncthreads();
    #pragma unroll
    for (int kt = 0; kt < 16; kt++) {
      const unsigned short* kp = Ks + (kt*16 + lid)*72 + quad*8;
      bf16x8 kb0 = *(const bf16x8*)kp;
      bf16x8 kb1 = *(const bf16x8*)(kp + 32);
      int ai = half*16 + kt;
      acc[ai] = __builtin_amdgcn_mfma_f32_16x16x32_bf16(qf0, kb0, acc[ai], 0, 0, 0);
      acc[ai] = __builtin_amdgcn_mfma_f32_16x16x32_bf16(qf1, kb1, acc[ai], 0, 0, 0);
    }
  }
  __syncthreads();   // K buffer dead; alias as row buffer

  float* Lw = smem + w*2080;           // per-wave [4 rows][520]
  float* pr = smem + 8320 + w*32;      // per-wave 16 e + 16 m

  #pragma unroll
  for (int r = 0; r < 4; r++) {
    // spill 4 rows (quad-indexed) of logits + bias to LDS
    int nq = q0 + w*16 + quad*4 + r;
    #pragma unroll
    for (int kt = 0; kt < 32; kt++) {
      int m = kt*16 + lid;
      Lw[quad*520 + m] = acc[kt][r] + bias_s[m - nq + 511];
    }
    __threadfence_block();
    #pragma unroll 1
    for (int g = 0; g < 4; g++) {
      int n = q0 + w*16 + g*4 + r;
      // pack: 23-bit monotonic value | 9-bit complemented index (unique, exact tie-break)
      unsigned pk[8];
      #pragma unroll
      for (int j = 0; j < 8; j++) {
        int m = l + j*64;
        unsigned mu = __float_as_uint(Lw[g*520 + m]);
        mu = (mu & 0x80000000u) ? ~mu : (mu | 0x80000000u);
        pk[j] = (mu & 0xFFFFFE00u) | (unsigned)(511 - m);
      }
      // row max of packed keys (monotonic) -> vmax for softmax stability
      unsigned bmax = pk[0];
      #pragma unroll
      for (int j = 1; j < 8; j++) bmax = pk[j] > bmax ? pk[j] : bmax;
      #pragma unroll
      for (int s2 = 1; s2 < 64; s2 <<= 1) {
        unsigned o2 = __shfl_xor(bmax, s2);
        bmax = o2 > bmax ? o2 : bmax;
      }
      // binary search for any T with count(pk >= T) == 16.
      // invariant: cnt(>=lo) >= 16, cnt(>=hi) < 16. keys unique => terminates
      // with cnt==16 within 32 halvings (at hi-lo==1, lo is the 16th key).
      unsigned lo = 0, hi = bmax;
      unsigned thr = 0;
      #pragma unroll 1
      for (int it = 0; it < 34; ++it) {
        unsigned mid = lo + ((hi - lo) >> 1);
        int cnt = 0;
        #pragma unroll
        for (int j = 0; j < 8; j++)
          cnt += (int)__popcll(__ballot(pk[j] >= mid));
        if (cnt == 16) { thr = mid; break; }
        if (cnt > 16) lo = mid; else hi = mid;
        thr = lo;
      }
      unsigned vu = bmax & 0xFFFFFE00u;
      vu = (vu & 0x80000000u) ? (vu & 0x7FFFFFFFu) : ~vu;
      float vmax = __uint_as_float(vu);
      // compact the exactly-16 survivors into pr; accumulate esum per-lane
      unsigned long long below = (1ull << l) - 1ull;
      int base = 0;
      float esum = 0.f;
      #pragma unroll
      for (int j = 0; j < 8; j++) {
        bool sel = pk[j] >= thr;
        unsigned long long mask = __ballot(sel);
        if (sel) {
          int slot = base + (int)__popcll(mask & below);
          unsigned vu2 = pk[j] & 0xFFFFFE00u;
          vu2 = (vu2 & 0x80000000u) ? (vu2 & 0x7FFFFFFFu) : ~vu2;
          float e = exp2f((__uint_as_float(vu2) - vmax) * 1.44269504f);
          esum += e;
          if (slot < 16) {
            pr[slot] = e;
            ((int*)pr)[16 + slot] = 511 - (int)(pk[j] & 0x1FFu);
          }
        }
        base += (int)__popcll(mask);
      }
      #pragma unroll
      for (int s2 = 1; s2 < 64; s2 <<= 1) esum += __shfl_xor(esum, s2);
      __threadfence_block();
      // sparse PV: lane = head dim
      float o = 0.f;
      float inv = 1.0f / esum;
      #pragma unroll
      for (int k2 = 0; k2 < 16; k2++) {
        float e = pr[k2];
        int m = ((const int*)pr)[16 + k2];
        o += e * bf2f(QKV[((size_t)(b*512 + m))*1536 + 1024 + h*64 + l]);
      }
      Aout[((size_t)(b*512 + n))*512 + h*64 + l] = f2bf(o * inv);
      __threadfence_block();   // pr reused next g
    }
  }
}

// ---------------- host ----------------
// ws budget (lifetime-aliased, ~46 MB total — R1 overflow corrupted pristine
// inputs when layout used ~102 MB):
//   W: weights bf16 (wqkvT 1.5M, woT 0.5M, w1T 2M, w2T 2M, bqkv 6K)
//   R1 (8 MB):  xn1 (ln1->gemm0) -> aout (attn->gemm1) -> xn2 (ln2->gemm2)
//   R2 (32 MB): qkvb in first 24 MB (gemm0->attn) -> hbuf full 32 MB (gemm2->gemm3)
//   x2 lives in d_out (gemm1 writes, ln2 reads, gemm3 same-addr RMW per element)
extern "C" void kernel_launch(void* const* d_in, const int* in_sizes, int n_in,
                              void* d_out, int out_size, void* d_ws, size_t ws_size,
                              hipStream_t stream) {
  const float* x   = (const float*)d_in[0];
  const float* wq  = (const float*)d_in[1];
  const float* bq  = (const float*)d_in[2];
  const float* wk  = (const float*)d_in[3];
  const float* bk  = (const float*)d_in[4];
  const float* wv  = (const float*)d_in[5];
  const float* bv  = (const float*)d_in[6];
  const float* wo  = (const float*)d_in[7];
  const float* bo  = (const float*)d_in[8];
  const float* g1  = (const float*)d_in[9];
  const float* be1 = (const float*)d_in[10];
  const float* g2  = (const float*)d_in[11];
  const float* be2 = (const float*)d_in[12];
  const float* w1  = (const float*)d_in[13];
  const float* bf1 = (const float*)d_in[14];
  const float* w2  = (const float*)d_in[15];
  const float* bf2 = (const float*)d_in[16];
  const float* rel = (const float*)d_in[17];

  char* p = (char*)d_ws;
  size_t off = 0;
  auto alloc = [&](size_t bytes) {
    size_t cur = off;
    off += (bytes + 255) & ~(size_t)255;
    return (void*)(p + cur);
  };
  unsigned short* wqkvT = (unsigned short*)alloc((size_t)1536*512*2);
  unsigned short* woT   = (unsigned short*)alloc((size_t)512*512*2);
  unsigned short* w1T   = (unsigned short*)alloc((size_t)2048*512*2);
  unsigned short* w2T   = (unsigned short*)alloc((size_t)512*2048*2);
  float*          bqkv  = (float*)alloc(1536*4);
  unsigned short* R1    = (unsigned short*)alloc((size_t)MM*512*2);   // 8MB
  unsigned short* R2    = (unsigned short*)alloc((size_t)MM*2048*2);  // 32MB

  unsigned short* xn1  = R1;                    // ln1 -> gemm0
  unsigned short* aout = R1;                    // attn -> gemm1 (xn1 dead)
  unsigned short* xn2  = R1;                    // ln2 -> gemm2 (aout dead)
  unsigned short* qkvb = R2;                    // gemm0 -> attn (24MB of 32)
  unsigned short* hbuf = R2;                    // gemm2 -> gemm3 (qkvb dead)
  float*          x2   = (float*)d_out;         // gemm1 -> ln2/gemm3
  (void)ws_size; (void)in_sizes; (void)n_in; (void)out_size;

  dim3 tb(32, 8);
  transpose_bf16<<<dim3(16, 16), tb, 0, stream>>>(wq, wqkvT,             512, 512);
  transpose_bf16<<<dim3(16, 16), tb, 0, stream>>>(wk, wqkvT + 512*512,   512, 512);
  transpose_bf16<<<dim3(16, 16), tb, 0, stream>>>(wv, wqkvT + 2*512*512, 512, 512);
  transpose_bf16<<<dim3(16, 16), tb, 0, stream>>>(wo, woT,               512, 512);
  transpose_bf16<<<dim3(64, 16), tb, 0, stream>>>(w1, w1T,  512, 2048);
  transpose_bf16<<<dim3(16, 64), tb, 0, stream>>>(w2, w2T, 2048,  512);
  concat_bias<<<6, 256, 0, stream>>>(bq, bk, bv, bqkv);

  ln_kernel<<<2048, 256, 0, stream>>>(x, g1, be1, xn1);
  gemm_kernel<0><<<dim3(12, 64), 256, 0, stream>>>(xn1, wqkvT, bqkv, nullptr, qkvb, MM, 1536, 512);
  attn_kernel<<<1024, 256, 0, stream>>>(qkvb, rel, aout);
  gemm_kernel<1><<<dim3(4, 64), 256, 0, stream>>>(aout, woT, bo, x, x2, MM, 512, 512);
  ln_kernel<<<2048, 256, 0, stream>>>(x2, g2, be2, xn2);
  gemm_kernel<2><<<dim3(16, 64), 256, 0, stream>>>(xn2, w1T, bf1, nullptr, hbuf, MM, 2048, 512);
  gemm_kernel<3><<<dim3(4, 64), 256, 0, stream>>>(hbuf, w2T, bf2, x2, (float*)d_out, MM, 512, 2048);
}

// Round 4
// 445.935 us; speedup vs baseline: 1.6691x; 1.2699x over previous
//
#include <hip/hip_runtime.h>
#include <hip/hip_bf16.h>

// B=16, N=512, D=512, H=8, HD=64, K(topk)=16, MSL=512
#define BB 16
#define NN 512
#define DD 512
#define HH 8
#define HD 64
#define MM (BB*NN)      // 8192 rows
#define DFF 2048

typedef __attribute__((ext_vector_type(8))) short bf16x8;
typedef __attribute__((ext_vector_type(4))) float fx4;

static __device__ __forceinline__ unsigned short f2bf(float f) {
  unsigned u = __float_as_uint(f);
  u += 0x7FFFu + ((u >> 16) & 1u);   // RNE
  return (unsigned short)(u >> 16);
}
static __device__ __forceinline__ float bf2f(unsigned short s) {
  return __uint_as_float(((unsigned)s) << 16);
}

// ---------------- weight transpose: in[K][N] fp32 -> out[N][K] bf16 ----------------
__global__ void transpose_bf16(const float* __restrict__ in, unsigned short* __restrict__ out,
                               int K, int N) {
  __shared__ float tl[32][33];
  int tx = threadIdx.x, ty = threadIdx.y;        // (32,8)
  int x0 = blockIdx.x * 32, y0 = blockIdx.y * 32;
  #pragma unroll
  for (int i = 0; i < 4; i++)
    tl[ty + i*8][tx] = in[(size_t)(y0 + ty + i*8) * N + x0 + tx];
  __syncthreads();
  #pragma unroll
  for (int i = 0; i < 4; i++)
    out[(size_t)(x0 + ty + i*8) * K + y0 + tx] = f2bf(tl[tx][ty + i*8]);
}

__global__ void concat_bias(const float* __restrict__ bq, const float* __restrict__ bk,
                            const float* __restrict__ bv, float* __restrict__ o) {
  int t = blockIdx.x * 256 + threadIdx.x;
  if (t < 512) o[t] = bq[t];
  else if (t < 1024) o[t] = bk[t - 512];
  else if (t < 1536) o[t] = bv[t - 1024];
}

// ---------------- LayerNorm: fp32 [rows][512] -> bf16 ----------------
__global__ __launch_bounds__(256) void ln_kernel(const float* __restrict__ X,
                                                 const float* __restrict__ g,
                                                 const float* __restrict__ be,
                                                 unsigned short* __restrict__ O) {
  int w = threadIdx.x >> 6, l = threadIdx.x & 63;
  size_t row = (size_t)blockIdx.x * 4 + w;
  const float* xr = X + row * 512;
  fx4 a = *(const fx4*)(xr + l*4);
  fx4 c = *(const fx4*)(xr + 256 + l*4);
  float s = a[0]+a[1]+a[2]+a[3] + c[0]+c[1]+c[2]+c[3];
  float q = a[0]*a[0]+a[1]*a[1]+a[2]*a[2]+a[3]*a[3]
          + c[0]*c[0]+c[1]*c[1]+c[2]*c[2]+c[3]*c[3];
  #pragma unroll
  for (int s2 = 1; s2 < 64; s2 <<= 1) { s += __shfl_xor(s, s2); q += __shfl_xor(q, s2); }
  float mean = s * (1.0f/512.0f);
  float var  = q * (1.0f/512.0f) - mean*mean;
  float rs = rsqrtf(var + 1e-5f);
  fx4 ga = *(const fx4*)(g + l*4);
  fx4 gc = *(const fx4*)(g + 256 + l*4);
  fx4 ba = *(const fx4*)(be + l*4);
  fx4 bc = *(const fx4*)(be + 256 + l*4);
  ushort4 o1, o2;
  o1.x = f2bf((a[0]-mean)*rs*ga[0] + ba[0]);
  o1.y = f2bf((a[1]-mean)*rs*ga[1] + ba[1]);
  o1.z = f2bf((a[2]-mean)*rs*ga[2] + ba[2]);
  o1.w = f2bf((a[3]-mean)*rs*ga[3] + ba[3]);
  o2.x = f2bf((c[0]-mean)*rs*gc[0] + bc[0]);
  o2.y = f2bf((c[1]-mean)*rs*gc[1] + bc[1]);
  o2.z = f2bf((c[2]-mean)*rs*gc[2] + bc[2]);
  o2.w = f2bf((c[3]-mean)*rs*gc[3] + bc[3]);
  *(ushort4*)(O + row*512 + l*4) = o1;
  *(ushort4*)(O + row*512 + 256 + l*4) = o2;
}

// ---------------- GEMM: C = A[M][K](bf16) x B^T rows [N][K](bf16) + epilogue ----------------
// MODE 0: +bqkv, cols<512 scaled by 0.125, out bf16   (QKV)
// MODE 1: +bias +resid -> fp32                        (out-proj + residual)
// MODE 2: +bias, exact GELU -> bf16                   (FFN1)
// MODE 3: +bias +resid -> fp32                        (FFN2 -> d_out; resid MAY ALIAS C)
template<int MODE>
__global__ __launch_bounds__(256) void gemm_kernel(
    const unsigned short* __restrict__ A,
    const unsigned short* __restrict__ Bm,
    const float* __restrict__ bias,
    const float* resid,           // no __restrict__: MODE 3 aliases resid == C
    void* C,
    int M, int N, int K) {
  __shared__ unsigned short As[128*40];   // stride 40 bf16 (80B, 16B aligned, ~2-way banks)
  __shared__ unsigned short Bs[128*40];
  int m0 = blockIdx.y * 128, n0 = blockIdx.x * 128;
  int t = threadIdx.x;
  int w = t >> 6, l = t & 63;
  int wm = w >> 1, wn = w & 1;
  int lid = l & 15, quad = l >> 4;

  fx4 acc[4][4];
  #pragma unroll
  for (int i = 0; i < 4; i++)
    #pragma unroll
    for (int j = 0; j < 4; j++) acc[i][j] = (fx4){0.f,0.f,0.f,0.f};

  for (int k0 = 0; k0 < K; k0 += 32) {
    #pragma unroll
    for (int i = 0; i < 2; i++) {
      int c = t + i*256;
      int row = c >> 2, ch = c & 3;
      uint4 da = *(const uint4*)(A  + (size_t)(m0+row)*K + k0 + ch*8);
      uint4 db = *(const uint4*)(Bm + (size_t)(n0+row)*K + k0 + ch*8);
      *(uint4*)(As + row*40 + ch*8) = da;
      *(uint4*)(Bs + row*40 + ch*8) = db;
    }
    __syncthreads();
    bf16x8 af[4], bf[4];
    #pragma unroll
    for (int i = 0; i < 4; i++) {
      af[i] = *(const bf16x8*)(As + (wm*64 + i*16 + lid)*40 + quad*8);
      bf[i] = *(const bf16x8*)(Bs + (wn*64 + i*16 + lid)*40 + quad*8);
    }
    #pragma unroll
    for (int i = 0; i < 4; i++)
      #pragma unroll
      for (int j = 0; j < 4; j++)
        acc[i][j] = __builtin_amdgcn_mfma_f32_16x16x32_bf16(af[i], bf[j], acc[i][j], 0, 0, 0);
    __syncthreads();
  }

  #pragma unroll
  for (int i = 0; i < 4; i++) {
    #pragma unroll
    for (int j = 0; j < 4; j++) {
      int col = n0 + wn*64 + j*16 + lid;
      float bv = bias[col];
      #pragma unroll
      for (int r = 0; r < 4; r++) {
        int row = m0 + wm*64 + i*16 + quad*4 + r;
        float v = acc[i][j][r] + bv;
        if (MODE == 0) {
          if (col < 512) v *= 0.125f;   // fold HD^-0.5 into Q
          ((unsigned short*)C)[(size_t)row*N + col] = f2bf(v);
        } else if (MODE == 1 || MODE == 3) {
          v += resid[(size_t)row*N + col];
          ((float*)C)[(size_t)row*N + col] = v;
        } else {  // MODE 2: exact GELU
          float gl = 0.5f * v * (1.0f + erff(v * 0.70710678118654752f));
          ((unsigned short*)C)[(size_t)row*N + col] = f2bf(gl);
        }
      }
    }
  }
}

// ---------------- fused attention: QK^T (MFMA) + rel bias + exact top-16 softmax + sparse PV ----------
// grid: 1024 blocks = (b,h) x 8 query-chunks of 64; block 256 thr = 4 waves x 16 queries
// R4: exploit MFMA C-layout — row (quad*4+r)'s 512 logits already live in quad-group
//     `quad`'s 16 lanes (m = kt*16+lid across acc[kt][r]). No LDS spill. All 16 rows
//     of a wave bisect SIMULTANEOUSLY (4 rows per group, counts packed 2x16-bit,
//     one 4-step group butterfly per iteration). Round-UP midpoint guarantees exact
//     cnt==16 termination. Compaction = deterministic ballot-prefix (bit-stable for
//     graph replay). PV: 16 lanes x 4 dims, esum folded into PV loop. No max-sub in
//     softmax (logits bounded; mathematically identical).
__global__ __launch_bounds__(256) void attn_kernel(
    const unsigned short* __restrict__ QKV,   // [8192][1536] bf16, Q pre-scaled
    const float* __restrict__ rel_emb,        // [1023][8]
    unsigned short* __restrict__ Aout) {      // [8192][512] bf16
  __shared__ float smem[10752];               // 42 KB
  unsigned short* Ks = (unsigned short*)smem; // [256][72] bf16 (floats 0..9215)
  float* bias_s = smem + 9216;                // [1023]
  float* pr = smem + 10240;                   // [4 waves][4 groups][16e+16m]
  int blk = blockIdx.x;
  int q0 = (blk & 7) << 6;
  int bh = blk >> 3;
  int b = bh >> 3, h = bh & 7;
  int t = threadIdx.x;
  int w = t >> 6, l = t & 63;
  int lid = l & 15, quad = l >> 4;

  for (int i = t; i < 1023; i += 256) bias_s[i] = rel_emb[i*8 + h];

  // Q fragments (A operand: m=lane&15, k=quad*8+j), two 32-wide k halves
  int qn = q0 + w*16 + lid;
  const unsigned short* qp = QKV + ((size_t)(b*512 + qn))*1536 + h*64 + quad*8;
  bf16x8 qf0 = *(const bf16x8*)qp;
  bf16x8 qf1 = *(const bf16x8*)(qp + 32);

  fx4 acc[32];
  #pragma unroll
  for (int i = 0; i < 32; i++) acc[i] = (fx4){0.f,0.f,0.f,0.f};

  #pragma unroll
  for (int half = 0; half < 2; half++) {
    __syncthreads();
    #pragma unroll
    for (int i = 0; i < 8; i++) {        // stage 256 keys x 64 dims bf16
      int c = t + i*256;
      int row = c >> 3, ch = c & 7;
      uint4 d = *(const uint4*)(QKV + ((size_t)(b*512 + half*256 + row))*1536 + 512 + h*64 + ch*8);
      *(uint4*)(Ks + row*72 + ch*8) = d;
    }
    __syncthreads();
    #pragma unroll
    for (int kt = 0; kt < 16; kt++) {
      const unsigned short* kp = Ks + (kt*16 + lid)*72 + quad*8;
      bf16x8 kb0 = *(const bf16x8*)kp;
      bf16x8 kb1 = *(const bf16x8*)(kp + 32);
      int ai = half*16 + kt;
      acc[ai] = __builtin_amdgcn_mfma_f32_16x16x32_bf16(qf0, kb0, acc[ai], 0, 0, 0);
      acc[ai] = __builtin_amdgcn_mfma_f32_16x16x32_bf16(qf1, kb1, acc[ai], 0, 0, 0);
    }
  }

  // ---- pack logits+bias into monotonic keys, in place in acc ----
  // key: 23-bit monotonic value | 9-bit complemented index (unique; exact
  // tie-break by lowest index, matching lax.top_k)
  int nb = q0 + w*16 + quad*4;   // first of this group's 4 rows
  #pragma unroll
  for (int kt = 0; kt < 32; kt++) {
    int m = kt*16 + lid;
    int bidx = m - nb + 511;
    #pragma unroll
    for (int r = 0; r < 4; r++) {
      float v = acc[kt][r] + bias_s[bidx - r];
      unsigned mu = __float_as_uint(v);
      mu = (mu & 0x80000000u) ? ~mu : (mu | 0x80000000u);
      acc[kt][r] = __uint_as_float((mu & 0xFFFFFE00u) | (unsigned)(511 - m));
    }
  }

  // ---- combined bisection: 16 rows per wave in parallel ----
  // invariant per row: cnt(>=lo) > 16 >= ... > cnt(>=hi); k16 in (lo, hi].
  // round-up mid tests hi when interval is 1 => guaranteed exact cnt==16 exit.
  unsigned lo0=0, lo1=0, lo2=0, lo3=0;
  unsigned hi0=0xFFFFFFFFu, hi1=0xFFFFFFFFu, hi2=0xFFFFFFFFu, hi3=0xFFFFFFFFu;
  unsigned th0=0, th1=0, th2=0, th3=0;
  unsigned done = 0;
  #pragma unroll 1
  for (int it = 0; it < 34; ++it) {
    unsigned d_;
    d_ = hi0-lo0; unsigned mid0 = lo0 + (d_>>1) + (d_&1u);
    d_ = hi1-lo1; unsigned mid1 = lo1 + (d_>>1) + (d_&1u);
    d_ = hi2-lo2; unsigned mid2 = lo2 + (d_>>1) + (d_&1u);
    d_ = hi3-lo3; unsigned mid3 = lo3 + (d_>>1) + (d_&1u);
    unsigned c0=0, c1=0, c2=0, c3=0;
    #pragma unroll
    for (int kt = 0; kt < 32; kt++) {
      c0 += (__float_as_uint(acc[kt][0]) >= mid0);
      c1 += (__float_as_uint(acc[kt][1]) >= mid1);
      c2 += (__float_as_uint(acc[kt][2]) >= mid2);
      c3 += (__float_as_uint(acc[kt][3]) >= mid3);
    }
    unsigned p01 = c0 | (c1 << 16);
    unsigned p23 = c2 | (c3 << 16);
    #pragma unroll
    for (int s2 = 1; s2 < 16; s2 <<= 1) {   // in-group butterfly (xor<16 stays in group)
      p01 += __shfl_xor(p01, s2);
      p23 += __shfl_xor(p23, s2);
    }
    unsigned C0 = p01 & 0xFFFFu, C1 = p01 >> 16;
    unsigned C2 = p23 & 0xFFFFu, C3 = p23 >> 16;
    { bool f = !(done & 1u); bool e = f && (C0 == 16u);
      th0 = e ? mid0 : th0; done |= e ? 1u : 0u;
      lo0 = (f && C0 > 16u) ? mid0 : lo0; hi0 = (f && C0 < 16u) ? mid0 : hi0; }
    { bool f = !(done & 2u); bool e = f && (C1 == 16u);
      th1 = e ? mid1 : th1; done |= e ? 2u : 0u;
      lo1 = (f && C1 > 16u) ? mid1 : lo1; hi1 = (f && C1 < 16u) ? mid1 : hi1; }
    { bool f = !(done & 4u); bool e = f && (C2 == 16u);
      th2 = e ? mid2 : th2; done |= e ? 4u : 0u;
      lo2 = (f && C2 > 16u) ? mid2 : lo2; hi2 = (f && C2 < 16u) ? mid2 : hi2; }
    { bool f = !(done & 8u); bool e = f && (C3 == 16u);
      th3 = e ? mid3 : th3; done |= e ? 8u : 0u;
      lo3 = (f && C3 > 16u) ? mid3 : lo3; hi3 = (f && C3 < 16u) ? mid3 : hi3; }
    if (__all((int)(done == 15u))) break;
  }

  // ---- per-row compaction (ballot-prefix, deterministic) + sparse PV ----
  float* prE = pr + w*128 + quad*32;
  int*   prM = (int*)prE + 16;
  unsigned below = (1u << lid) - 1u;
  #pragma unroll
  for (int r = 0; r < 4; r++) {
    unsigned thr = (r==0) ? th0 : (r==1) ? th1 : (r==2) ? th2 : th3;
    int base = 0;
    #pragma unroll
    for (int kt = 0; kt < 32; kt++) {
      unsigned u = __float_as_uint(acc[kt][r]);
      bool sel = u >= thr;
      unsigned long long bm = __ballot(sel);
      unsigned gm = (unsigned)(bm >> (quad*16)) & 0xFFFFu;
      if (sel) {
        int slot = base + __popc(gm & below);
        unsigned vu = u & 0xFFFFFE00u;
        vu = (vu & 0x80000000u) ? (vu & 0x7FFFFFFFu) : ~vu;
        float e = exp2f(__uint_as_float(vu) * 1.44269504f);
        if (slot < 16) { prE[slot] = e; prM[slot] = 511 - (int)(u & 0x1FFu); }
      }
      base += __popc(gm);
    }
    __threadfence_block();
    int n = nb + r;
    float o0=0.f, o1=0.f, o2=0.f, o3=0.f, es=0.f;
    #pragma unroll
    for (int k2 = 0; k2 < 16; k2++) {
      float e = prE[k2];
      int m = prM[k2];
      const unsigned short* vp = QKV + ((size_t)(b*512 + m))*1536 + 1024 + h*64 + lid*4;
      ushort4 v4 = *(const ushort4*)vp;
      es += e;
      o0 += e * bf2f(v4.x); o1 += e * bf2f(v4.y);
      o2 += e * bf2f(v4.z); o3 += e * bf2f(v4.w);
    }
    float inv = 1.0f / es;
    ushort4 ov;
    ov.x = f2bf(o0*inv); ov.y = f2bf(o1*inv);
    ov.z = f2bf(o2*inv); ov.w = f2bf(o3*inv);
    *(ushort4*)(Aout + ((size_t)(b*512 + n))*512 + h*64 + lid*4) = ov;
    __threadfence_block();   // pr reused next r (wave-internal ordering)
  }
}

// ---------------- host ----------------
// ws budget (lifetime-aliased, ~46 MB total — R1 overflow corrupted pristine
// inputs when layout used ~102 MB):
//   W: weights bf16 (wqkvT 1.5M, woT 0.5M, w1T 2M, w2T 2M, bqkv 6K)
//   R1 (8 MB):  xn1 (ln1->gemm0) -> aout (attn->gemm1) -> xn2 (ln2->gemm2)
//   R2 (32 MB): qkvb in first 24 MB (gemm0->attn) -> hbuf full 32 MB (gemm2->gemm3)
//   x2 lives in d_out (gemm1 writes, ln2 reads, gemm3 same-addr RMW per element)
extern "C" void kernel_launch(void* const* d_in, const int* in_sizes, int n_in,
                              void* d_out, int out_size, void* d_ws, size_t ws_size,
                              hipStream_t stream) {
  const float* x   = (const float*)d_in[0];
  const float* wq  = (const float*)d_in[1];
  const float* bq  = (const float*)d_in[2];
  const float* wk  = (const float*)d_in[3];
  const float* bk  = (const float*)d_in[4];
  const float* wv  = (const float*)d_in[5];
  const float* bv  = (const float*)d_in[6];
  const float* wo  = (const float*)d_in[7];
  const float* bo  = (const float*)d_in[8];
  const float* g1  = (const float*)d_in[9];
  const float* be1 = (const float*)d_in[10];
  const float* g2  = (const float*)d_in[11];
  const float* be2 = (const float*)d_in[12];
  const float* w1  = (const float*)d_in[13];
  const float* bf1 = (const float*)d_in[14];
  const float* w2  = (const float*)d_in[15];
  const float* bf2 = (const float*)d_in[16];
  const float* rel = (const float*)d_in[17];

  char* p = (char*)d_ws;
  size_t off = 0;
  auto alloc = [&](size_t bytes) {
    size_t cur = off;
    off += (bytes + 255) & ~(size_t)255;
    return (void*)(p + cur);
  };
  unsigned short* wqkvT = (unsigned short*)alloc((size_t)1536*512*2);
  unsigned short* woT   = (unsigned short*)alloc((size_t)512*512*2);
  unsigned short* w1T   = (unsigned short*)alloc((size_t)2048*512*2);
  unsigned short* w2T   = (unsigned short*)alloc((size_t)512*2048*2);
  float*          bqkv  = (float*)alloc(1536*4);
  unsigned short* R1    = (unsigned short*)alloc((size_t)MM*512*2);   // 8MB
  unsigned short* R2    = (unsigned short*)alloc((size_t)MM*2048*2);  // 32MB

  unsigned short* xn1  = R1;                    // ln1 -> gemm0
  unsigned short* aout = R1;                    // attn -> gemm1 (xn1 dead)
  unsigned short* xn2  = R1;                    // ln2 -> gemm2 (aout dead)
  unsigned short* qkvb = R2;                    // gemm0 -> attn (24MB of 32)
  unsigned short* hbuf = R2;                    // gemm2 -> gemm3 (qkvb dead)
  float*          x2   = (float*)d_out;         // gemm1 -> ln2/gemm3
  (void)ws_size; (void)in_sizes; (void)n_in; (void)out_size;

  dim3 tb(32, 8);
  transpose_bf16<<<dim3(16, 16), tb, 0, stream>>>(wq, wqkvT,             512, 512);
  transpose_bf16<<<dim3(16, 16), tb, 0, stream>>>(wk, wqkvT + 512*512,   512, 512);
  transpose_bf16<<<dim3(16, 16), tb, 0, stream>>>(wv, wqkvT + 2*512*512, 512, 512);
  transpose_bf16<<<dim3(16, 16), tb, 0, stream>>>(wo, woT,               512, 512);
  transpose_bf16<<<dim3(64, 16), tb, 0, stream>>>(w1, w1T,  512, 2048);
  transpose_bf16<<<dim3(16, 64), tb, 0, stream>>>(w2, w2T, 2048,  512);
  concat_bias<<<6, 256, 0, stream>>>(bq, bk, bv, bqkv);

  ln_kernel<<<2048, 256, 0, stream>>>(x, g1, be1, xn1);
  gemm_kernel<0><<<dim3(12, 64), 256, 0, stream>>>(xn1, wqkvT, bqkv, nullptr, qkvb, MM, 1536, 512);
  attn_kernel<<<1024, 256, 0, stream>>>(qkvb, rel, aout);
  gemm_kernel<1><<<dim3(4, 64), 256, 0, stream>>>(aout, woT, bo, x, x2, MM, 512, 512);
  ln_kernel<<<2048, 256, 0, stream>>>(x2, g2, be2, xn2);
  gemm_kernel<2><<<dim3(16, 64), 256, 0, stream>>>(xn2, w1T, bf1, nullptr, hbuf, MM, 2048, 512);
  gemm_kernel<3><<<dim3(4, 64), 256, 0, stream>>>(hbuf, w2T, bf2, x2, (float*)d_out, MM, 512, 2048);
}

// Round 5
// 427.396 us; speedup vs baseline: 1.7415x; 1.0434x over previous
//
#include <hip/hip_runtime.h>
#include <hip/hip_bf16.h>

// B=16, N=512, D=512, H=8, HD=64, K(topk)=16, MSL=512
#define BB 16
#define NN 512
#define DD 512
#define HH 8
#define HD 64
#define MM (BB*NN)      // 8192 rows
#define DFF 2048

typedef __attribute__((ext_vector_type(8))) short bf16x8;
typedef __attribute__((ext_vector_type(4))) float fx4;

static __device__ __forceinline__ unsigned short f2bf(float f) {
  unsigned u = __float_as_uint(f);
  u += 0x7FFFu + ((u >> 16) & 1u);   // RNE
  return (unsigned short)(u >> 16);
}
static __device__ __forceinline__ float bf2f(unsigned short s) {
  return __uint_as_float(((unsigned)s) << 16);
}

// async global->LDS DMA, 16B/lane, dest = wave-uniform base + lane*16
static __device__ __forceinline__ void load_lds16(const unsigned short* g, unsigned short* l) {
  __builtin_amdgcn_global_load_lds(
      (const __attribute__((address_space(1))) void*)g,
      (__attribute__((address_space(3))) void*)l, 16, 0, 0);
}

// ---------------- weight transpose: in[K][N] fp32 -> out[N][K] bf16 ----------------
__global__ void transpose_bf16(const float* __restrict__ in, unsigned short* __restrict__ out,
                               int K, int N) {
  __shared__ float tl[32][33];
  int tx = threadIdx.x, ty = threadIdx.y;        // (32,8)
  int x0 = blockIdx.x * 32, y0 = blockIdx.y * 32;
  #pragma unroll
  for (int i = 0; i < 4; i++)
    tl[ty + i*8][tx] = in[(size_t)(y0 + ty + i*8) * N + x0 + tx];
  __syncthreads();
  #pragma unroll
  for (int i = 0; i < 4; i++)
    out[(size_t)(x0 + ty + i*8) * K + y0 + tx] = f2bf(tl[tx][ty + i*8]);
}

__global__ void concat_bias(const float* __restrict__ bq, const float* __restrict__ bk,
                            const float* __restrict__ bv, float* __restrict__ o) {
  int t = blockIdx.x * 256 + threadIdx.x;
  if (t < 512) o[t] = bq[t];
  else if (t < 1024) o[t] = bk[t - 512];
  else if (t < 1536) o[t] = bv[t - 1024];
}

// ---------------- LayerNorm: fp32 [rows][512] -> bf16 ----------------
__global__ __launch_bounds__(256) void ln_kernel(const float* __restrict__ X,
                                                 const float* __restrict__ g,
                                                 const float* __restrict__ be,
                                                 unsigned short* __restrict__ O) {
  int w = threadIdx.x >> 6, l = threadIdx.x & 63;
  size_t row = (size_t)blockIdx.x * 4 + w;
  const float* xr = X + row * 512;
  fx4 a = *(const fx4*)(xr + l*4);
  fx4 c = *(const fx4*)(xr + 256 + l*4);
  float s = a[0]+a[1]+a[2]+a[3] + c[0]+c[1]+c[2]+c[3];
  float q = a[0]*a[0]+a[1]*a[1]+a[2]*a[2]+a[3]*a[3]
          + c[0]*c[0]+c[1]*c[1]+c[2]*c[2]+c[3]*c[3];
  #pragma unroll
  for (int s2 = 1; s2 < 64; s2 <<= 1) { s += __shfl_xor(s, s2); q += __shfl_xor(q, s2); }
  float mean = s * (1.0f/512.0f);
  float var  = q * (1.0f/512.0f) - mean*mean;
  float rs = rsqrtf(var + 1e-5f);
  fx4 ga = *(const fx4*)(g + l*4);
  fx4 gc = *(const fx4*)(g + 256 + l*4);
  fx4 ba = *(const fx4*)(be + l*4);
  fx4 bc = *(const fx4*)(be + 256 + l*4);
  ushort4 o1, o2;
  o1.x = f2bf((a[0]-mean)*rs*ga[0] + ba[0]);
  o1.y = f2bf((a[1]-mean)*rs*ga[1] + ba[1]);
  o1.z = f2bf((a[2]-mean)*rs*ga[2] + ba[2]);
  o1.w = f2bf((a[3]-mean)*rs*ga[3] + ba[3]);
  o2.x = f2bf((c[0]-mean)*rs*gc[0] + bc[0]);
  o2.y = f2bf((c[1]-mean)*rs*gc[1] + bc[1]);
  o2.z = f2bf((c[2]-mean)*rs*gc[2] + bc[2]);
  o2.w = f2bf((c[3]-mean)*rs*gc[3] + bc[3]);
  *(ushort4*)(O + row*512 + l*4) = o1;
  *(ushort4*)(O + row*512 + 256 + l*4) = o2;
}

// ---------------- GEMM (R5: m97 structure) ----------------
// C[M][N] = A[M][K](bf16) x B^T rows [N][K](bf16) + epilogue.
// 128 x TN tile, 4 waves. TN=128: 2x2 waves, 64x64/wave, acc 4x4.
//                         TN=64:  4x1 waves, 32x64/wave, acc 2x4 (for N=512 -> 2 blocks/CU).
// Staging via global_load_lds width=16 into UNPADDED LDS [row][32 bf16]:
// lane L of wave w writes (base + L*16B) = row w*16+L/4, 16B-chunk L%4 (m104/m108
// contiguity rule). __syncthreads() provides the vmcnt(0) drain (m97 pattern).
// MODE 0: +bqkv, cols<512 scaled 0.125, out bf16 (QKV)
// MODE 1: +bias +resid -> fp32 (out-proj + residual)
// MODE 2: +bias, exact GELU -> bf16 (FFN1)
// MODE 3: +bias +resid -> fp32 (FFN2 -> d_out; resid MAY ALIAS C)
template<int MODE, int TN>
__global__ __launch_bounds__(256) void gemm_kernel(
    const unsigned short* __restrict__ A,
    const unsigned short* __restrict__ Bm,
    const float* __restrict__ bias,
    const float* resid,           // no __restrict__: MODE 3 aliases resid == C
    void* C,
    int M, int N, int K) {
  constexpr int MI = (TN == 128) ? 4 : 2;   // m-fragments per wave
  constexpr int WM = (TN == 128) ? 64 : 32; // wave m-extent
  __shared__ unsigned short As[128*32];     // 8 KB
  __shared__ unsigned short Bs[TN*32];      // 8 or 4 KB
  int m0 = blockIdx.y * 128, n0 = blockIdx.x * TN;
  int t = threadIdx.x;
  int w = t >> 6, l = t & 63;
  int wm = (TN == 128) ? (w >> 1) : w;
  int wn = (TN == 128) ? (w & 1) : 0;
  int lid = l & 15, quad = l >> 4;
  int lrow = l >> 2, lch = l & 3;

  // staging sources: wave w covers rows [w*16, w*16+16) (+64 for second inst)
  const unsigned short* gA0 = A  + (size_t)(m0 + w*16 + lrow)*K + lch*8;
  const unsigned short* gA1 = gA0 + (size_t)64*K;
  const unsigned short* gB0 = Bm + (size_t)(n0 + w*16 + lrow)*K + lch*8;
  const unsigned short* gB1 = (TN == 128) ? gB0 + (size_t)64*K : nullptr;
  unsigned short* lA0 = As + w*512;
  unsigned short* lA1 = As + 2048 + w*512;
  unsigned short* lB0 = Bs + w*512;
  unsigned short* lB1 = (TN == 128) ? Bs + 2048 + w*512 : nullptr;

  fx4 acc[MI][4];
  #pragma unroll
  for (int i = 0; i < MI; i++)
    #pragma unroll
    for (int j = 0; j < 4; j++) acc[i][j] = (fx4){0.f,0.f,0.f,0.f};

  for (int k0 = 0; k0 < K; k0 += 32) {
    load_lds16(gA0, lA0);
    load_lds16(gA1, lA1);
    load_lds16(gB0, lB0);
    if constexpr (TN == 128) load_lds16(gB1, lB1);
    gA0 += 32; gA1 += 32; gB0 += 32;
    if constexpr (TN == 128) gB1 += 32;
    __syncthreads();                 // vmcnt(0) drain + barrier (m97)
    bf16x8 af[MI], bf[4];
    #pragma unroll
    for (int i = 0; i < MI; i++)
      af[i] = *(const bf16x8*)(As + (wm*WM + i*16 + lid)*32 + quad*8);
    #pragma unroll
    for (int j = 0; j < 4; j++)
      bf[j] = *(const bf16x8*)(Bs + (wn*64 + j*16 + lid)*32 + quad*8);
    #pragma unroll
    for (int i = 0; i < MI; i++)
      #pragma unroll
      for (int j = 0; j < 4; j++)
        acc[i][j] = __builtin_amdgcn_mfma_f32_16x16x32_bf16(af[i], bf[j], acc[i][j], 0, 0, 0);
    __syncthreads();
  }

  #pragma unroll
  for (int i = 0; i < MI; i++) {
    #pragma unroll
    for (int j = 0; j < 4; j++) {
      int col = n0 + wn*64 + j*16 + lid;
      float bv = bias[col];
      #pragma unroll
      for (int r = 0; r < 4; r++) {
        int row = m0 + wm*WM + i*16 + quad*4 + r;
        float v = acc[i][j][r] + bv;
        if (MODE == 0) {
          if (col < 512) v *= 0.125f;   // fold HD^-0.5 into Q
          ((unsigned short*)C)[(size_t)row*N + col] = f2bf(v);
        } else if (MODE == 1 || MODE == 3) {
          v += resid[(size_t)row*N + col];
          ((float*)C)[(size_t)row*N + col] = v;
        } else {  // MODE 2: exact GELU
          float gl = 0.5f * v * (1.0f + erff(v * 0.70710678118654752f));
          ((unsigned short*)C)[(size_t)row*N + col] = f2bf(gl);
        }
      }
    }
  }
}

// ---------------- fused attention: QK^T (MFMA) + rel bias + exact top-16 softmax + sparse PV ----------
// grid: 1024 blocks = (b,h) x 8 query-chunks of 64; block 256 thr = 4 waves x 16 queries
// R4: logits stay in MFMA C-layout registers; 16 rows/wave bisect simultaneously
//     (counts packed 2x16-bit, 4-step group butterfly). Round-up midpoint => exact
//     cnt==16 termination. Ballot-prefix compaction (deterministic). PV 16 lanes x 4 dims.
__global__ __launch_bounds__(256) void attn_kernel(
    const unsigned short* __restrict__ QKV,   // [8192][1536] bf16, Q pre-scaled
    const float* __restrict__ rel_emb,        // [1023][8]
    unsigned short* __restrict__ Aout) {      // [8192][512] bf16
  __shared__ float smem[10752];               // 42 KB
  unsigned short* Ks = (unsigned short*)smem; // [256][72] bf16
  float* bias_s = smem + 9216;                // [1023]
  float* pr = smem + 10240;                   // [4 waves][4 groups][16e+16m]
  int blk = blockIdx.x;
  int q0 = (blk & 7) << 6;
  int bh = blk >> 3;
  int b = bh >> 3, h = bh & 7;
  int t = threadIdx.x;
  int w = t >> 6, l = t & 63;
  int lid = l & 15, quad = l >> 4;

  for (int i = t; i < 1023; i += 256) bias_s[i] = rel_emb[i*8 + h];

  int qn = q0 + w*16 + lid;
  const unsigned short* qp = QKV + ((size_t)(b*512 + qn))*1536 + h*64 + quad*8;
  bf16x8 qf0 = *(const bf16x8*)qp;
  bf16x8 qf1 = *(const bf16x8*)(qp + 32);

  fx4 acc[32];
  #pragma unroll
  for (int i = 0; i < 32; i++) acc[i] = (fx4){0.f,0.f,0.f,0.f};

  #pragma unroll
  for (int half = 0; half < 2; half++) {
    __syncthreads();
    #pragma unroll
    for (int i = 0; i < 8; i++) {        // stage 256 keys x 64 dims bf16
      int c = t + i*256;
      int row = c >> 3, ch = c & 7;
      uint4 d = *(const uint4*)(QKV + ((size_t)(b*512 + half*256 + row))*1536 + 512 + h*64 + ch*8);
      *(uint4*)(Ks + row*72 + ch*8) = d;
    }
    __syncthreads();
    #pragma unroll
    for (int kt = 0; kt < 16; kt++) {
      const unsigned short* kp = Ks + (kt*16 + lid)*72 + quad*8;
      bf16x8 kb0 = *(const bf16x8*)kp;
      bf16x8 kb1 = *(const bf16x8*)(kp + 32);
      int ai = half*16 + kt;
      acc[ai] = __builtin_amdgcn_mfma_f32_16x16x32_bf16(qf0, kb0, acc[ai], 0, 0, 0);
      acc[ai] = __builtin_amdgcn_mfma_f32_16x16x32_bf16(qf1, kb1, acc[ai], 0, 0, 0);
    }
  }

  // ---- pack logits+bias into monotonic keys, in place in acc ----
  int nb = q0 + w*16 + quad*4;   // first of this group's 4 rows
  #pragma unroll
  for (int kt = 0; kt < 32; kt++) {
    int m = kt*16 + lid;
    int bidx = m - nb + 511;
    #pragma unroll
    for (int r = 0; r < 4; r++) {
      float v = acc[kt][r] + bias_s[bidx - r];
      unsigned mu = __float_as_uint(v);
      mu = (mu & 0x80000000u) ? ~mu : (mu | 0x80000000u);
      acc[kt][r] = __uint_as_float((mu & 0xFFFFFE00u) | (unsigned)(511 - m));
    }
  }

  // ---- combined bisection: 16 rows per wave in parallel ----
  unsigned lo0=0, lo1=0, lo2=0, lo3=0;
  unsigned hi0=0xFFFFFFFFu, hi1=0xFFFFFFFFu, hi2=0xFFFFFFFFu, hi3=0xFFFFFFFFu;
  unsigned th0=0, th1=0, th2=0, th3=0;
  unsigned done = 0;
  #pragma unroll 1
  for (int it = 0; it < 34; ++it) {
    unsigned d_;
    d_ = hi0-lo0; unsigned mid0 = lo0 + (d_>>1) + (d_&1u);
    d_ = hi1-lo1; unsigned mid1 = lo1 + (d_>>1) + (d_&1u);
    d_ = hi2-lo2; unsigned mid2 = lo2 + (d_>>1) + (d_&1u);
    d_ = hi3-lo3; unsigned mid3 = lo3 + (d_>>1) + (d_&1u);
    unsigned c0=0, c1=0, c2=0, c3=0;
    #pragma unroll
    for (int kt = 0; kt < 32; kt++) {
      c0 += (__float_as_uint(acc[kt][0]) >= mid0);
      c1 += (__float_as_uint(acc[kt][1]) >= mid1);
      c2 += (__float_as_uint(acc[kt][2]) >= mid2);
      c3 += (__float_as_uint(acc[kt][3]) >= mid3);
    }
    unsigned p01 = c0 | (c1 << 16);
    unsigned p23 = c2 | (c3 << 16);
    #pragma unroll
    for (int s2 = 1; s2 < 16; s2 <<= 1) {   // in-group butterfly
      p01 += __shfl_xor(p01, s2);
      p23 += __shfl_xor(p23, s2);
    }
    unsigned C0 = p01 & 0xFFFFu, C1 = p01 >> 16;
    unsigned C2 = p23 & 0xFFFFu, C3 = p23 >> 16;
    { bool f = !(done & 1u); bool e = f && (C0 == 16u);
      th0 = e ? mid0 : th0; done |= e ? 1u : 0u;
      lo0 = (f && C0 > 16u) ? mid0 : lo0; hi0 = (f && C0 < 16u) ? mid0 : hi0; }
    { bool f = !(done & 2u); bool e = f && (C1 == 16u);
      th1 = e ? mid1 : th1; done |= e ? 2u : 0u;
      lo1 = (f && C1 > 16u) ? mid1 : lo1; hi1 = (f && C1 < 16u) ? mid1 : hi1; }
    { bool f = !(done & 4u); bool e = f && (C2 == 16u);
      th2 = e ? mid2 : th2; done |= e ? 4u : 0u;
      lo2 = (f && C2 > 16u) ? mid2 : lo2; hi2 = (f && C2 < 16u) ? mid2 : hi2; }
    { bool f = !(done & 8u); bool e = f && (C3 == 16u);
      th3 = e ? mid3 : th3; done |= e ? 8u : 0u;
      lo3 = (f && C3 > 16u) ? mid3 : lo3; hi3 = (f && C3 < 16u) ? mid3 : hi3; }
    if (__all((int)(done == 15u))) break;
  }

  // ---- per-row compaction (ballot-prefix, deterministic) + sparse PV ----
  float* prE = pr + w*128 + quad*32;
  int*   prM = (int*)prE + 16;
  unsigned below = (1u << lid) - 1u;
  #pragma unroll
  for (int r = 0; r < 4; r++) {
    unsigned thr = (r==0) ? th0 : (r==1) ? th1 : (r==2) ? th2 : th3;
    int base = 0;
    #pragma unroll
    for (int kt = 0; kt < 32; kt++) {
      unsigned u = __float_as_uint(acc[kt][r]);
      bool sel = u >= thr;
      unsigned long long bm = __ballot(sel);
      unsigned gm = (unsigned)(bm >> (quad*16)) & 0xFFFFu;
      if (sel) {
        int slot = base + __popc(gm & below);
        unsigned vu = u & 0xFFFFFE00u;
        vu = (vu & 0x80000000u) ? (vu & 0x7FFFFFFFu) : ~vu;
        float e = exp2f(__uint_as_float(vu) * 1.44269504f);
        if (slot < 16) { prE[slot] = e; prM[slot] = 511 - (int)(u & 0x1FFu); }
      }
      base += __popc(gm);
    }
    __threadfence_block();
    int n = nb + r;
    float o0=0.f, o1=0.f, o2=0.f, o3=0.f, es=0.f;
    #pragma unroll
    for (int k2 = 0; k2 < 16; k2++) {
      float e = prE[k2];
      int m = prM[k2];
      const unsigned short* vp = QKV + ((size_t)(b*512 + m))*1536 + 1024 + h*64 + lid*4;
      ushort4 v4 = *(const ushort4*)vp;
      es += e;
      o0 += e * bf2f(v4.x); o1 += e * bf2f(v4.y);
      o2 += e * bf2f(v4.z); o3 += e * bf2f(v4.w);
    }
    float inv = 1.0f / es;
    ushort4 ov;
    ov.x = f2bf(o0*inv); ov.y = f2bf(o1*inv);
    ov.z = f2bf(o2*inv); ov.w = f2bf(o3*inv);
    *(ushort4*)(Aout + ((size_t)(b*512 + n))*512 + h*64 + lid*4) = ov;
    __threadfence_block();   // pr reused next r
  }
}

// ---------------- host ----------------
// ws budget (lifetime-aliased, ~46 MB — R1 overflow corrupted pristine inputs):
//   R1 (8 MB):  xn1 -> aout -> xn2
//   R2 (32 MB): qkvb (24 MB) -> hbuf
//   x2 lives in d_out (gemm1 writes, ln2 reads, gemm3 same-addr RMW per element)
extern "C" void kernel_launch(void* const* d_in, const int* in_sizes, int n_in,
                              void* d_out, int out_size, void* d_ws, size_t ws_size,
                              hipStream_t stream) {
  const float* x   = (const float*)d_in[0];
  const float* wq  = (const float*)d_in[1];
  const float* bq  = (const float*)d_in[2];
  const float* wk  = (const float*)d_in[3];
  const float* bk  = (const float*)d_in[4];
  const float* wv  = (const float*)d_in[5];
  const float* bv  = (const float*)d_in[6];
  const float* wo  = (const float*)d_in[7];
  const float* bo  = (const float*)d_in[8];
  const float* g1  = (const float*)d_in[9];
  const float* be1 = (const float*)d_in[10];
  const float* g2  = (const float*)d_in[11];
  const float* be2 = (const float*)d_in[12];
  const float* w1  = (const float*)d_in[13];
  const float* bf1 = (const float*)d_in[14];
  const float* w2  = (const float*)d_in[15];
  const float* bf2 = (const float*)d_in[16];
  const float* rel = (const float*)d_in[17];

  char* p = (char*)d_ws;
  size_t off = 0;
  auto alloc = [&](size_t bytes) {
    size_t cur = off;
    off += (bytes + 255) & ~(size_t)255;
    return (void*)(p + cur);
  };
  unsigned short* wqkvT = (unsigned short*)alloc((size_t)1536*512*2);
  unsigned short* woT   = (unsigned short*)alloc((size_t)512*512*2);
  unsigned short* w1T   = (unsigned short*)alloc((size_t)2048*512*2);
  unsigned short* w2T   = (unsigned short*)alloc((size_t)512*2048*2);
  float*          bqkv  = (float*)alloc(1536*4);
  unsigned short* R1    = (unsigned short*)alloc((size_t)MM*512*2);   // 8MB
  unsigned short* R2    = (unsigned short*)alloc((size_t)MM*2048*2);  // 32MB

  unsigned short* xn1  = R1;                    // ln1 -> gemm0
  unsigned short* aout = R1;                    // attn -> gemm1 (xn1 dead)
  unsigned short* xn2  = R1;                    // ln2 -> gemm2 (aout dead)
  unsigned short* qkvb = R2;                    // gemm0 -> attn (24MB of 32)
  unsigned short* hbuf = R2;                    // gemm2 -> gemm3 (qkvb dead)
  float*          x2   = (float*)d_out;         // gemm1 -> ln2/gemm3
  (void)ws_size; (void)in_sizes; (void)n_in; (void)out_size;

  dim3 tb(32, 8);
  transpose_bf16<<<dim3(16, 16), tb, 0, stream>>>(wq, wqkvT,             512, 512);
  transpose_bf16<<<dim3(16, 16), tb, 0, stream>>>(wk, wqkvT + 512*512,   512, 512);
  transpose_bf16<<<dim3(16, 16), tb, 0, stream>>>(wv, wqkvT + 2*512*512, 512, 512);
  transpose_bf16<<<dim3(16, 16), tb, 0, stream>>>(wo, woT,               512, 512);
  transpose_bf16<<<dim3(64, 16), tb, 0, stream>>>(w1, w1T,  512, 2048);
  transpose_bf16<<<dim3(16, 64), tb, 0, stream>>>(w2, w2T, 2048,  512);
  concat_bias<<<6, 256, 0, stream>>>(bq, bk, bv, bqkv);

  ln_kernel<<<2048, 256, 0, stream>>>(x, g1, be1, xn1);
  gemm_kernel<0,128><<<dim3(12, 64), 256, 0, stream>>>(xn1, wqkvT, bqkv, nullptr, qkvb, MM, 1536, 512);
  attn_kernel<<<1024, 256, 0, stream>>>(qkvb, rel, aout);
  gemm_kernel<1,64><<<dim3(8, 64), 256, 0, stream>>>(aout, woT, bo, x, x2, MM, 512, 512);
  ln_kernel<<<2048, 256, 0, stream>>>(x2, g2, be2, xn2);
  gemm_kernel<2,128><<<dim3(16, 64), 256, 0, stream>>>(xn2, w1T, bf1, nullptr, hbuf, MM, 2048, 512);
  gemm_kernel<3,64><<<dim3(8, 64), 256, 0, stream>>>(hbuf, w2T, bf2, x2, (float*)d_out, MM, 512, 2048);
}

// Round 6
// 411.590 us; speedup vs baseline: 1.8083x; 1.0384x over previous
//
#include <hip/hip_runtime.h>
#include <hip/hip_bf16.h>

// B=16, N=512, D=512, H=8, HD=64, K(topk)=16, MSL=512
#define BB 16
#define NN 512
#define DD 512
#define HH 8
#define HD 64
#define MM (BB*NN)      // 8192 rows
#define DFF 2048

typedef __attribute__((ext_vector_type(8))) short bf16x8;
typedef __attribute__((ext_vector_type(4))) float fx4;

static __device__ __forceinline__ unsigned short f2bf(float f) {
  unsigned u = __float_as_uint(f);
  u += 0x7FFFu + ((u >> 16) & 1u);   // RNE
  return (unsigned short)(u >> 16);
}
static __device__ __forceinline__ float bf2f(unsigned short s) {
  return __uint_as_float(((unsigned)s) << 16);
}

// async global->LDS DMA, 16B/lane, dest = wave-uniform base + lane*16
static __device__ __forceinline__ void load_lds16(const unsigned short* g, unsigned short* l) {
  __builtin_amdgcn_global_load_lds(
      (const __attribute__((address_space(1))) void*)g,
      (__attribute__((address_space(3))) void*)l, 16, 0, 0);
}

// ---------------- fused weight transpose: 6 matrices [K][N] fp32 -> [N][K] bf16 ----------------
// one dispatch; tile id -> (matrix, tile). 1024 tiles for the four 512x512,
// 1024 for w1 (512x2048), 1024 for w2 (2048x512).
__global__ void transpose_all(const float* __restrict__ wq, const float* __restrict__ wk,
                              const float* __restrict__ wv, const float* __restrict__ wo,
                              const float* __restrict__ w1, const float* __restrict__ w2,
                              unsigned short* __restrict__ wqkvT, unsigned short* __restrict__ woT,
                              unsigned short* __restrict__ w1T, unsigned short* __restrict__ w2T) {
  __shared__ float tl[32][33];
  int id = blockIdx.x;
  const float* src; unsigned short* dst; int K, N, bx, by;
  if (id < 1024) {
    int m = id >> 8, tt = id & 255;
    src = (m == 0) ? wq : (m == 1) ? wk : (m == 2) ? wv : wo;
    dst = (m == 3) ? woT : wqkvT + m * 512 * 512;
    K = 512; N = 512; bx = tt & 15; by = tt >> 4;
  } else if (id < 2048) {
    int tt = id - 1024;
    src = w1; dst = w1T; K = 512; N = 2048; bx = tt & 63; by = tt >> 6;
  } else {
    int tt = id - 2048;
    src = w2; dst = w2T; K = 2048; N = 512; bx = tt & 15; by = tt >> 4;
  }
  int tx = threadIdx.x, ty = threadIdx.y;        // (32,8)
  int x0 = bx * 32, y0 = by * 32;
  #pragma unroll
  for (int i = 0; i < 4; i++)
    tl[ty + i*8][tx] = src[(size_t)(y0 + ty + i*8) * N + x0 + tx];
  __syncthreads();
  #pragma unroll
  for (int i = 0; i < 4; i++)
    dst[(size_t)(x0 + ty + i*8) * K + y0 + tx] = f2bf(tl[tx][ty + i*8]);
}

__global__ void concat_bias(const float* __restrict__ bq, const float* __restrict__ bk,
                            const float* __restrict__ bv, float* __restrict__ o) {
  int t = blockIdx.x * 256 + threadIdx.x;
  if (t < 512) o[t] = bq[t];
  else if (t < 1024) o[t] = bk[t - 512];
  else if (t < 1536) o[t] = bv[t - 1024];
}

// ---------------- LayerNorm: fp32 [rows][512] -> bf16 ----------------
__global__ __launch_bounds__(256) void ln_kernel(const float* __restrict__ X,
                                                 const float* __restrict__ g,
                                                 const float* __restrict__ be,
                                                 unsigned short* __restrict__ O) {
  int w = threadIdx.x >> 6, l = threadIdx.x & 63;
  size_t row = (size_t)blockIdx.x * 4 + w;
  const float* xr = X + row * 512;
  fx4 a = *(const fx4*)(xr + l*4);
  fx4 c = *(const fx4*)(xr + 256 + l*4);
  float s = a[0]+a[1]+a[2]+a[3] + c[0]+c[1]+c[2]+c[3];
  float q = a[0]*a[0]+a[1]*a[1]+a[2]*a[2]+a[3]*a[3]
          + c[0]*c[0]+c[1]*c[1]+c[2]*c[2]+c[3]*c[3];
  #pragma unroll
  for (int s2 = 1; s2 < 64; s2 <<= 1) { s += __shfl_xor(s, s2); q += __shfl_xor(q, s2); }
  float mean = s * (1.0f/512.0f);
  float var  = q * (1.0f/512.0f) - mean*mean;
  float rs = rsqrtf(var + 1e-5f);
  fx4 ga = *(const fx4*)(g + l*4);
  fx4 gc = *(const fx4*)(g + 256 + l*4);
  fx4 ba = *(const fx4*)(be + l*4);
  fx4 bc = *(const fx4*)(be + 256 + l*4);
  ushort4 o1, o2;
  o1.x = f2bf((a[0]-mean)*rs*ga[0] + ba[0]);
  o1.y = f2bf((a[1]-mean)*rs*ga[1] + ba[1]);
  o1.z = f2bf((a[2]-mean)*rs*ga[2] + ba[2]);
  o1.w = f2bf((a[3]-mean)*rs*ga[3] + ba[3]);
  o2.x = f2bf((c[0]-mean)*rs*gc[0] + bc[0]);
  o2.y = f2bf((c[1]-mean)*rs*gc[1] + bc[1]);
  o2.z = f2bf((c[2]-mean)*rs*gc[2] + bc[2]);
  o2.w = f2bf((c[3]-mean)*rs*gc[3] + bc[3]);
  *(ushort4*)(O + row*512 + l*4) = o1;
  *(ushort4*)(O + row*512 + 256 + l*4) = o2;
}

// ---------------- GEMM (R6: short-K latency-tolerant tiles) ----------------
// C[M][N] = A[M][K](bf16) x B^T rows [N][K](bf16) + epilogue.
// TM=64, BK=64, 4 waves. TN=128: waves 2x2 (32x64 each, acc 2x4); TN=64: waves
// 4x1 (16x64, acc 1x4). Blocks: gemm0 1536, gemm2 2048, gemm1/3 1024 ->
// 4-8 blocks/CU resident (vs 2-3 in R5) to hide the per-iteration vmcnt(0)
// barrier drain; BK=64 halves barrier count (8 iters @K=512).
// XOR-swizzled staging: global_load_lds forces LDS row-major (dest = base +
// lane*16), so lane L fetches global chunk (L&7)^(L>>3); slot s of row r then
// holds chunk s^(r&7). Fragment ds_read xors by lid&7 -> 2-way banks (free,
// m136) instead of 8-way. Data bit-identical; layout-only.
// MODE 0: +bqkv, cols<512 scaled 0.125, out bf16 (QKV)
// MODE 1: +bias +resid -> fp32 (out-proj + residual)
// MODE 2: +bias, exact GELU -> bf16 (FFN1)
// MODE 3: +bias +resid -> fp32 (FFN2 -> d_out; resid MAY ALIAS C)
template<int MODE, int TN>
__global__ __launch_bounds__(256) void gemm_kernel(
    const unsigned short* __restrict__ A,
    const unsigned short* __restrict__ Bm,
    const float* __restrict__ bias,
    const float* resid,           // no __restrict__: MODE 3 aliases resid == C
    void* C,
    int M, int N, int K) {
  constexpr int MI  = (TN == 128) ? 2 : 1;    // m-fragments per wave
  constexpr int BW  = (TN == 128) ? 32 : 16;  // B rows staged per wave
  constexpr int NBI = (TN == 128) ? 4 : 2;    // B staging insts per wave
  __shared__ unsigned short As[64*64];        // 8 KB
  __shared__ unsigned short Bs[TN*64];        // 16 or 8 KB
  int m0 = blockIdx.y * 64, n0 = blockIdx.x * TN;
  int t = threadIdx.x;
  int w = t >> 6, l = t & 63;
  int wm = (TN == 128) ? (w >> 1) : w;        // wave m index
  int wn = (TN == 128) ? (w & 1) : 0;
  int lid = l & 15, quad = l >> 4;
  int lrow = l >> 3, lch = (l & 7) ^ lrow;    // xor-swizzled source chunk

  // per-lane global staging pointers (advance by BK per iteration)
  const unsigned short* gA = A  + (size_t)(m0 + w*16 + lrow)*K + lch*8;
  const unsigned short* gB = Bm + (size_t)(n0 + w*BW + lrow)*K + lch*8;
  // wave-uniform LDS staging bases
  unsigned short* lA0 = As + (w*16    )*64;
  unsigned short* lA1 = As + (w*16 + 8)*64;
  unsigned short* lB[NBI];
  #pragma unroll
  for (int i = 0; i < NBI; i++) lB[i] = Bs + (w*BW + i*8)*64;

  fx4 acc[MI][4];
  #pragma unroll
  for (int i = 0; i < MI; i++)
    #pragma unroll
    for (int j = 0; j < 4; j++) acc[i][j] = (fx4){0.f,0.f,0.f,0.f};

  int xA = (lid & 7) * 8;   // fragment-read xor offset (elements), row&7 == lid&7

  for (int k0 = 0; k0 < K; k0 += 64) {
    load_lds16(gA,       lA0);
    load_lds16(gA + 8*K, lA1);
    #pragma unroll
    for (int i = 0; i < NBI; i++) load_lds16(gB + (size_t)(i*8)*K, lB[i]);
    gA += 64; gB += 64;
    __syncthreads();                 // vmcnt(0) drain + barrier (m97 pattern)
    #pragma unroll
    for (int s = 0; s < 2; s++) {
      int cbase = (s*4 + quad) * 8;  // global chunk (elements) within the 64-wide K slab
      bf16x8 af[MI], bf[4];
      #pragma unroll
      for (int i = 0; i < MI; i++) {
        int ra = wm*(MI*16) + i*16 + lid;
        af[i] = *(const bf16x8*)(As + ra*64 + (cbase ^ xA));
      }
      #pragma unroll
      for (int j = 0; j < 4; j++) {
        int rb = wn*64 + j*16 + lid;
        bf[j] = *(const bf16x8*)(Bs + rb*64 + (cbase ^ xA));
      }
      #pragma unroll
      for (int i = 0; i < MI; i++)
        #pragma unroll
        for (int j = 0; j < 4; j++)
          acc[i][j] = __builtin_amdgcn_mfma_f32_16x16x32_bf16(af[i], bf[j], acc[i][j], 0, 0, 0);
    }
    __syncthreads();
  }

  #pragma unroll
  for (int i = 0; i < MI; i++) {
    #pragma unroll
    for (int j = 0; j < 4; j++) {
      int col = n0 + wn*64 + j*16 + lid;
      float bv = bias[col];
      #pragma unroll
      for (int r = 0; r < 4; r++) {
        int row = m0 + wm*(MI*16) + i*16 + quad*4 + r;
        float v = acc[i][j][r] + bv;
        if (MODE == 0) {
          if (col < 512) v *= 0.125f;   // fold HD^-0.5 into Q
          ((unsigned short*)C)[(size_t)row*N + col] = f2bf(v);
        } else if (MODE == 1 || MODE == 3) {
          v += resid[(size_t)row*N + col];
          ((float*)C)[(size_t)row*N + col] = v;
        } else {  // MODE 2: exact GELU
          float gl = 0.5f * v * (1.0f + erff(v * 0.70710678118654752f));
          ((unsigned short*)C)[(size_t)row*N + col] = f2bf(gl);
        }
      }
    }
  }
}

// ---------------- fused attention: QK^T (MFMA) + rel bias + exact top-16 softmax + sparse PV ----------
// grid: 1024 blocks = (b,h) x 8 query-chunks of 64; block 256 thr = 4 waves x 16 queries
// R4: logits stay in MFMA C-layout registers; 16 rows/wave bisect simultaneously
//     (counts packed 2x16-bit, 4-step group butterfly). Round-up midpoint => exact
//     cnt==16 termination. Ballot-prefix compaction (deterministic). PV 16 lanes x 4 dims.
__global__ __launch_bounds__(256) void attn_kernel(
    const unsigned short* __restrict__ QKV,   // [8192][1536] bf16, Q pre-scaled
    const float* __restrict__ rel_emb,        // [1023][8]
    unsigned short* __restrict__ Aout) {      // [8192][512] bf16
  __shared__ float smem[10752];               // 42 KB
  unsigned short* Ks = (unsigned short*)smem; // [256][72] bf16
  float* bias_s = smem + 9216;                // [1023]
  float* pr = smem + 10240;                   // [4 waves][4 groups][16e+16m]
  int blk = blockIdx.x;
  int q0 = (blk & 7) << 6;
  int bh = blk >> 3;
  int b = bh >> 3, h = bh & 7;
  int t = threadIdx.x;
  int w = t >> 6, l = t & 63;
  int lid = l & 15, quad = l >> 4;

  for (int i = t; i < 1023; i += 256) bias_s[i] = rel_emb[i*8 + h];

  int qn = q0 + w*16 + lid;
  const unsigned short* qp = QKV + ((size_t)(b*512 + qn))*1536 + h*64 + quad*8;
  bf16x8 qf0 = *(const bf16x8*)qp;
  bf16x8 qf1 = *(const bf16x8*)(qp + 32);

  fx4 acc[32];
  #pragma unroll
  for (int i = 0; i < 32; i++) acc[i] = (fx4){0.f,0.f,0.f,0.f};

  #pragma unroll
  for (int half = 0; half < 2; half++) {
    __syncthreads();
    #pragma unroll
    for (int i = 0; i < 8; i++) {        // stage 256 keys x 64 dims bf16
      int c = t + i*256;
      int row = c >> 3, ch = c & 7;
      uint4 d = *(const uint4*)(QKV + ((size_t)(b*512 + half*256 + row))*1536 + 512 + h*64 + ch*8);
      *(uint4*)(Ks + row*72 + ch*8) = d;
    }
    __syncthreads();
    #pragma unroll
    for (int kt = 0; kt < 16; kt++) {
      const unsigned short* kp = Ks + (kt*16 + lid)*72 + quad*8;
      bf16x8 kb0 = *(const bf16x8*)kp;
      bf16x8 kb1 = *(const bf16x8*)(kp + 32);
      int ai = half*16 + kt;
      acc[ai] = __builtin_amdgcn_mfma_f32_16x16x32_bf16(qf0, kb0, acc[ai], 0, 0, 0);
      acc[ai] = __builtin_amdgcn_mfma_f32_16x16x32_bf16(qf1, kb1, acc[ai], 0, 0, 0);
    }
  }

  // ---- pack logits+bias into monotonic keys, in place in acc ----
  int nb = q0 + w*16 + quad*4;   // first of this group's 4 rows
  #pragma unroll
  for (int kt = 0; kt < 32; kt++) {
    int m = kt*16 + lid;
    int bidx = m - nb + 511;
    #pragma unroll
    for (int r = 0; r < 4; r++) {
      float v = acc[kt][r] + bias_s[bidx - r];
      unsigned mu = __float_as_uint(v);
      mu = (mu & 0x80000000u) ? ~mu : (mu | 0x80000000u);
      acc[kt][r] = __uint_as_float((mu & 0xFFFFFE00u) | (unsigned)(511 - m));
    }
  }

  // ---- combined bisection: 16 rows per wave in parallel ----
  unsigned lo0=0, lo1=0, lo2=0, lo3=0;
  unsigned hi0=0xFFFFFFFFu, hi1=0xFFFFFFFFu, hi2=0xFFFFFFFFu, hi3=0xFFFFFFFFu;
  unsigned th0=0, th1=0, th2=0, th3=0;
  unsigned done = 0;
  #pragma unroll 1
  for (int it = 0; it < 34; ++it) {
    unsigned d_;
    d_ = hi0-lo0; unsigned mid0 = lo0 + (d_>>1) + (d_&1u);
    d_ = hi1-lo1; unsigned mid1 = lo1 + (d_>>1) + (d_&1u);
    d_ = hi2-lo2; unsigned mid2 = lo2 + (d_>>1) + (d_&1u);
    d_ = hi3-lo3; unsigned mid3 = lo3 + (d_>>1) + (d_&1u);
    unsigned c0=0, c1=0, c2=0, c3=0;
    #pragma unroll
    for (int kt = 0; kt < 32; kt++) {
      c0 += (__float_as_uint(acc[kt][0]) >= mid0);
      c1 += (__float_as_uint(acc[kt][1]) >= mid1);
      c2 += (__float_as_uint(acc[kt][2]) >= mid2);
      c3 += (__float_as_uint(acc[kt][3]) >= mid3);
    }
    unsigned p01 = c0 | (c1 << 16);
    unsigned p23 = c2 | (c3 << 16);
    #pragma unroll
    for (int s2 = 1; s2 < 16; s2 <<= 1) {   // in-group butterfly
      p01 += __shfl_xor(p01, s2);
      p23 += __shfl_xor(p23, s2);
    }
    unsigned C0 = p01 & 0xFFFFu, C1 = p01 >> 16;
    unsigned C2 = p23 & 0xFFFFu, C3 = p23 >> 16;
    { bool f = !(done & 1u); bool e = f && (C0 == 16u);
      th0 = e ? mid0 : th0; done |= e ? 1u : 0u;
      lo0 = (f && C0 > 16u) ? mid0 : lo0; hi0 = (f && C0 < 16u) ? mid0 : hi0; }
    { bool f = !(done & 2u); bool e = f && (C1 == 16u);
      th1 = e ? mid1 : th1; done |= e ? 2u : 0u;
      lo1 = (f && C1 > 16u) ? mid1 : lo1; hi1 = (f && C1 < 16u) ? mid1 : hi1; }
    { bool f = !(done & 4u); bool e = f && (C2 == 16u);
      th2 = e ? mid2 : th2; done |= e ? 4u : 0u;
      lo2 = (f && C2 > 16u) ? mid2 : lo2; hi2 = (f && C2 < 16u) ? mid2 : hi2; }
    { bool f = !(done & 8u); bool e = f && (C3 == 16u);
      th3 = e ? mid3 : th3; done |= e ? 8u : 0u;
      lo3 = (f && C3 > 16u) ? mid3 : lo3; hi3 = (f && C3 < 16u) ? mid3 : hi3; }
    if (__all((int)(done == 15u))) break;
  }

  // ---- per-row compaction (ballot-prefix, deterministic) + sparse PV ----
  float* prE = pr + w*128 + quad*32;
  int*   prM = (int*)prE + 16;
  unsigned below = (1u << lid) - 1u;
  #pragma unroll
  for (int r = 0; r < 4; r++) {
    unsigned thr = (r==0) ? th0 : (r==1) ? th1 : (r==2) ? th2 : th3;
    int base = 0;
    #pragma unroll
    for (int kt = 0; kt < 32; kt++) {
      unsigned u = __float_as_uint(acc[kt][r]);
      bool sel = u >= thr;
      unsigned long long bm = __ballot(sel);
      unsigned gm = (unsigned)(bm >> (quad*16)) & 0xFFFFu;
      if (sel) {
        int slot = base + __popc(gm & below);
        unsigned vu = u & 0xFFFFFE00u;
        vu = (vu & 0x80000000u) ? (vu & 0x7FFFFFFFu) : ~vu;
        float e = exp2f(__uint_as_float(vu) * 1.44269504f);
        if (slot < 16) { prE[slot] = e; prM[slot] = 511 - (int)(u & 0x1FFu); }
      }
      base += __popc(gm);
    }
    __threadfence_block();
    int n = nb + r;
    float o0=0.f, o1=0.f, o2=0.f, o3=0.f, es=0.f;
    #pragma unroll
    for (int k2 = 0; k2 < 16; k2++) {
      float e = prE[k2];
      int m = prM[k2];
      const unsigned short* vp = QKV + ((size_t)(b*512 + m))*1536 + 1024 + h*64 + lid*4;
      ushort4 v4 = *(const ushort4*)vp;
      es += e;
      o0 += e * bf2f(v4.x); o1 += e * bf2f(v4.y);
      o2 += e * bf2f(v4.z); o3 += e * bf2f(v4.w);
    }
    float inv = 1.0f / es;
    ushort4 ov;
    ov.x = f2bf(o0*inv); ov.y = f2bf(o1*inv);
    ov.z = f2bf(o2*inv); ov.w = f2bf(o3*inv);
    *(ushort4*)(Aout + ((size_t)(b*512 + n))*512 + h*64 + lid*4) = ov;
    __threadfence_block();   // pr reused next r
  }
}

// ---------------- host ----------------
// ws budget (lifetime-aliased, ~46 MB — R1 overflow corrupted pristine inputs):
//   R1 (8 MB):  xn1 -> aout -> xn2
//   R2 (32 MB): qkvb (24 MB) -> hbuf
//   x2 lives in d_out (gemm1 writes, ln2 reads, gemm3 same-addr RMW per element)
extern "C" void kernel_launch(void* const* d_in, const int* in_sizes, int n_in,
                              void* d_out, int out_size, void* d_ws, size_t ws_size,
                              hipStream_t stream) {
  const float* x   = (const float*)d_in[0];
  const float* wq  = (const float*)d_in[1];
  const float* bq  = (const float*)d_in[2];
  const float* wk  = (const float*)d_in[3];
  const float* bk  = (const float*)d_in[4];
  const float* wv  = (const float*)d_in[5];
  const float* bv  = (const float*)d_in[6];
  const float* wo  = (const float*)d_in[7];
  const float* bo  = (const float*)d_in[8];
  const float* g1  = (const float*)d_in[9];
  const float* be1 = (const float*)d_in[10];
  const float* g2  = (const float*)d_in[11];
  const float* be2 = (const float*)d_in[12];
  const float* w1  = (const float*)d_in[13];
  const float* bf1 = (const float*)d_in[14];
  const float* w2  = (const float*)d_in[15];
  const float* bf2 = (const float*)d_in[16];
  const float* rel = (const float*)d_in[17];

  char* p = (char*)d_ws;
  size_t off = 0;
  auto alloc = [&](size_t bytes) {
    size_t cur = off;
    off += (bytes + 255) & ~(size_t)255;
    return (void*)(p + cur);
  };
  unsigned short* wqkvT = (unsigned short*)alloc((size_t)1536*512*2);
  unsigned short* woT   = (unsigned short*)alloc((size_t)512*512*2);
  unsigned short* w1T   = (unsigned short*)alloc((size_t)2048*512*2);
  unsigned short* w2T   = (unsigned short*)alloc((size_t)512*2048*2);
  float*          bqkv  = (float*)alloc(1536*4);
  unsigned short* R1    = (unsigned short*)alloc((size_t)MM*512*2);   // 8MB
  unsigned short* R2    = (unsigned short*)alloc((size_t)MM*2048*2);  // 32MB

  unsigned short* xn1  = R1;                    // ln1 -> gemm0
  unsigned short* aout = R1;                    // attn -> gemm1 (xn1 dead)
  unsigned short* xn2  = R1;                    // ln2 -> gemm2 (aout dead)
  unsigned short* qkvb = R2;                    // gemm0 -> attn (24MB of 32)
  unsigned short* hbuf = R2;                    // gemm2 -> gemm3 (qkvb dead)
  float*          x2   = (float*)d_out;         // gemm1 -> ln2/gemm3
  (void)ws_size; (void)in_sizes; (void)n_in; (void)out_size;

  transpose_all<<<3072, dim3(32, 8), 0, stream>>>(wq, wk, wv, wo, w1, w2,
                                                  wqkvT, woT, w1T, w2T);
  concat_bias<<<6, 256, 0, stream>>>(bq, bk, bv, bqkv);

  ln_kernel<<<2048, 256, 0, stream>>>(x, g1, be1, xn1);
  gemm_kernel<0,128><<<dim3(12, 128), 256, 0, stream>>>(xn1, wqkvT, bqkv, nullptr, qkvb, MM, 1536, 512);
  attn_kernel<<<1024, 256, 0, stream>>>(qkvb, rel, aout);
  gemm_kernel<1,64><<<dim3(8, 128), 256, 0, stream>>>(aout, woT, bo, x, x2, MM, 512, 512);
  ln_kernel<<<2048, 256, 0, stream>>>(x2, g2, be2, xn2);
  gemm_kernel<2,128><<<dim3(16, 128), 256, 0, stream>>>(xn2, w1T, bf1, nullptr, hbuf, MM, 2048, 512);
  gemm_kernel<3,64><<<dim3(8, 128), 256, 0, stream>>>(hbuf, w2T, bf2, x2, (float*)d_out, MM, 512, 2048);
}